// Round 1
// baseline (829.946 us; speedup 1.0000x reference)
//
#include <hip/hip_runtime.h>
#include <hip/hip_bf16.h>

typedef __hip_bfloat16 bf16;
typedef __attribute__((ext_vector_type(8))) short bfrag8;  // 8 bf16 = 4 VGPRs
typedef __attribute__((ext_vector_type(4))) float f4;

#define NN 32704      // total nodes = 64 trees * 511
#define PT 511        // nodes per tree
#define NT 64         // trees
#define XD 640        // MEM_DIM

__device__ __forceinline__ float sigmoidf_(float x) { return 1.0f / (1.0f + expf(-x)); }

// ---------------- converts ----------------
__global__ void cvt_kernel(const float* __restrict__ src, bf16* __restrict__ dst, int n) {
    int i = blockIdx.x * blockDim.x + threadIdx.x;
    int stride = gridDim.x * blockDim.x;
    for (; i < n; i += stride) dst[i] = __float2bfloat16(src[i]);
}

// src[K][Nc] f32 -> dst[Nc][K] bf16  (transpose so MFMA B-fragments are contiguous in k)
__global__ void cvt_t_kernel(const float* __restrict__ src, bf16* __restrict__ dst, int K, int Nc) {
    int i = blockIdx.x * blockDim.x + threadIdx.x;
    int stride = gridDim.x * blockDim.x;
    int total = K * Nc;
    for (; i < total; i += stride) {
        int n = i / K, k = i - n * K;
        dst[i] = __float2bfloat16(src[k * Nc + n]);
    }
}

// ---------------- generic GEMM: C = act(A @ B + bias), bf16 in/out, f32 acc ----------------
// A: [M][lda] bf16 row-major (use rows blockIdx.x*64..+64)
// Bt: [Ncols][K] bf16 (i.e. B transposed), ldb == K
// grid: (M/64, Ncols/64), block 256 (4 waves, each 32x32 via 2x2 16x16x32 frags)
template <int ACT>
__global__ __launch_bounds__(256) void gemm_kernel(
    const bf16* __restrict__ A, int lda,
    const bf16* __restrict__ Bt, int K,
    const float* __restrict__ bias,
    bf16* __restrict__ C, int ldc)
{
    int tid = threadIdx.x;
    int lane = tid & 63, w = tid >> 6;
    int row0 = blockIdx.x * 64 + (w >> 1) * 32;
    int col0 = blockIdx.y * 64 + (w & 1) * 32;
    int am = lane & 15, ak = (lane >> 4) * 8;

    f4 acc[2][2] = {};
    for (int k0 = 0; k0 < K; k0 += 32) {
        bfrag8 a[2] = {}, b[2] = {};
        bool kin = (k0 + ak) < K;   // only matters for K=16 (card MLP)
        if (kin) {
#pragma unroll
            for (int f = 0; f < 2; ++f) {
                a[f] = *(const bfrag8*)(A + (size_t)(row0 + f * 16 + am) * lda + k0 + ak);
                b[f] = *(const bfrag8*)(Bt + (size_t)(col0 + f * 16 + am) * K + k0 + ak);
            }
        }
#pragma unroll
        for (int fm = 0; fm < 2; ++fm)
#pragma unroll
            for (int fn = 0; fn < 2; ++fn)
                acc[fm][fn] = __builtin_amdgcn_mfma_f32_16x16x32_bf16(a[fm], b[fn], acc[fm][fn], 0, 0, 0);
    }

    int rbase = (lane >> 4) * 4;
#pragma unroll
    for (int fm = 0; fm < 2; ++fm)
#pragma unroll
        for (int fn = 0; fn < 2; ++fn)
#pragma unroll
            for (int r = 0; r < 4; ++r) {
                int row = row0 + fm * 16 + rbase + r;
                int col = col0 + fn * 16 + am;
                float v = acc[fm][fn][r] + bias[col];
                if (ACT) v = fmaxf(v, 0.0f);
                C[(size_t)row * ldc + col] = __float2bfloat16(v);
            }
}

// ---------------- xou GEMM with fused gate epilogue ----------------
// X: [NN][640] bf16. Wt: [1920][640] bf16 (w_xou transposed). Computes the three
// 640-wide column regions (xx, ff, rr) together per tile so the epilogue can fuse:
//   ff_out = sigmoid(ff), rr_out = sigmoid(rr) (bf16), c0 = (1-ff)*xx -> c output.
// grid: (511, 10), block 256.
__global__ __launch_bounds__(256) void xou_kernel(
    const bf16* __restrict__ X,
    const bf16* __restrict__ Wt,
    const float* __restrict__ bias,   // [1920]
    float* __restrict__ ffp,          // [NN][640] f32
    bf16* __restrict__ rrp,           // [NN][640] bf16
    float* __restrict__ cc)           // [NN][640] f32 (the c output region)
{
    int tid = threadIdx.x;
    int lane = tid & 63, w = tid >> 6;
    int row0 = blockIdx.x * 64 + (w >> 1) * 32;
    int col0 = blockIdx.y * 64 + (w & 1) * 32;
    int am = lane & 15, ak = (lane >> 4) * 8;

    f4 acc[3][2][2] = {};
    for (int k0 = 0; k0 < 640; k0 += 32) {
        bfrag8 a[2], b[3][2];
#pragma unroll
        for (int f = 0; f < 2; ++f)
            a[f] = *(const bfrag8*)(X + (size_t)(row0 + f * 16 + am) * XD + k0 + ak);
#pragma unroll
        for (int q = 0; q < 3; ++q)
#pragma unroll
            for (int f = 0; f < 2; ++f)
                b[q][f] = *(const bfrag8*)(Wt + (size_t)(q * 640 + col0 + f * 16 + am) * XD + k0 + ak);
#pragma unroll
        for (int q = 0; q < 3; ++q)
#pragma unroll
            for (int fm = 0; fm < 2; ++fm)
#pragma unroll
                for (int fn = 0; fn < 2; ++fn)
                    acc[q][fm][fn] = __builtin_amdgcn_mfma_f32_16x16x32_bf16(a[fm], b[q][fn], acc[q][fm][fn], 0, 0, 0);
    }

    int rbase = (lane >> 4) * 4;
#pragma unroll
    for (int fm = 0; fm < 2; ++fm)
#pragma unroll
        for (int fn = 0; fn < 2; ++fn)
#pragma unroll
            for (int r = 0; r < 4; ++r) {
                int row = row0 + fm * 16 + rbase + r;
                int col = col0 + fn * 16 + am;
                size_t o = (size_t)row * XD + col;
                float xx = acc[0][fm][fn][r] + bias[col];
                float fv = sigmoidf_(acc[1][fm][fn][r] + bias[640 + col]);
                float rv = sigmoidf_(acc[2][fm][fn][r] + bias[1280 + col]);
                ffp[o] = fv;
                rrp[o] = __float2bfloat16(rv);
                cc[o] = (1.0f - fv) * xx;   // leaf value AND the additive term at every level
            }
}

// ---------------- tree recursion, one launch per level ----------------
// Level n parents (per tree): local idx in [cnt-1, 2*cnt-1), cnt = 2^(8-n).
// c[p] = ff[p]*(c[left]+c[right]) + c[p]   (c[p] currently holds (1-ff)*xx)
__global__ void level_kernel(float* __restrict__ c, const float* __restrict__ ff, int cnt) {
    int idx = blockIdx.x * 256 + threadIdx.x;
    int total = NT * cnt * XD;
    if (idx >= total) return;
    int d = idx % XD;
    int p = idx / XD;
    int t = p / cnt, rk = p - t * cnt;
    int pl = (cnt - 1) + rk;
    size_t g = (size_t)(t * PT + pl) * XD + d;
    size_t cl = (size_t)(t * PT + 2 * pl + 1) * XD + d;
    float cs = c[cl] + c[cl + XD];
    c[g] = ff[g] * cs + c[g];
}

// ---------------- h = rr*tanh(c) + (1-rr)*x  (all nodes, after recursion) ----------------
__global__ void h_kernel(const float* __restrict__ c, const bf16* __restrict__ rr,
                         const bf16* __restrict__ x, bf16* __restrict__ h) {
    size_t i = (size_t)blockIdx.x * 256 + threadIdx.x;
    if (i >= (size_t)NN * XD) return;
    float rv = __bfloat162float(rr[i]);
    float xv = __bfloat162float(x[i]);
    h[i] = __float2bfloat16(rv * tanhf(c[i]) + (1.0f - rv) * xv);
}

// ---------------- out = sigmoid(hid2 . w_o2 + b_o2), one wave per row ----------------
__global__ __launch_bounds__(256) void out_kernel(const bf16* __restrict__ h2,
                                                  const float* __restrict__ w2,
                                                  const float* __restrict__ b2,
                                                  float* __restrict__ out) {
    int lane = threadIdx.x & 63;
    int row = blockIdx.x * 4 + (threadIdx.x >> 6);
    const bf16* hr = h2 + (size_t)row * 512 + lane * 8;
    bfrag8 hv = *(const bfrag8*)hr;
    float s = 0.0f;
#pragma unroll
    for (int j = 0; j < 8; ++j)
        s += __bfloat162float(((const bf16*)&hv)[j]) * w2[lane * 8 + j];
#pragma unroll
    for (int off = 32; off; off >>= 1) s += __shfl_down(s, off, 64);
    if (lane == 0) out[row] = 1.0f / (1.0f + expf(-(s + b2[0])));
}

// ---------------- host ----------------
extern "C" void kernel_launch(void* const* d_in, const int* in_sizes, int n_in,
                              void* d_out, int out_size, void* d_ws, size_t ws_size,
                              hipStream_t stream) {
    const int din[5] = {32, 64, 256, 128, 16};

    const float* feats[5];
    const float *w1f[5], *b1f[5], *w2f[5], *b2f[5];
    for (int t = 0; t < 5; ++t) {
        feats[t] = (const float*)d_in[t];
        w1f[t] = (const float*)d_in[8 + 4 * t];
        b1f[t] = (const float*)d_in[9 + 4 * t];
        w2f[t] = (const float*)d_in[10 + 4 * t];
        b2f[t] = (const float*)d_in[11 + 4 * t];
    }
    const float* w_xou = (const float*)d_in[28];
    const float* b_xou = (const float*)d_in[29];
    const float* w_o1  = (const float*)d_in[30];
    const float* b_o1  = (const float*)d_in[31];
    const float* w_o2  = (const float*)d_in[32];
    const float* b_o2  = (const float*)d_in[33];

    float* outp = (float*)d_out;        // [NN]
    float* cc   = (float*)d_out + NN;   // [NN][640]

    // workspace layout (~245 MB)
    char* ws = (char*)d_ws;
    size_t off = 0;
    auto take = [&](size_t bytes) -> char* {
        char* p = ws + off;
        off += (bytes + 255) & ~(size_t)255;
        return p;
    };
    bf16* w1t[5]; for (int t = 0; t < 5; ++t) w1t[t] = (bf16*)take((size_t)128 * din[t] * 2);
    bf16* w2t[5]; for (int t = 0; t < 5; ++t) w2t[t] = (bf16*)take((size_t)128 * 128 * 2);
    bf16* wxout = (bf16*)take((size_t)1920 * 640 * 2);
    bf16* wo1t  = (bf16*)take((size_t)512 * 640 * 2);
    bf16* featb[5]; for (int t = 0; t < 5; ++t) featb[t] = (bf16*)take((size_t)NN * din[t] * 2);
    bf16* hid1 = (bf16*)take((size_t)NN * XD * 2);   // later reused as h (bf16)
    bf16* xbf  = (bf16*)take((size_t)NN * XD * 2);   // later reused as hid2 (NN x 512)
    float* ffb = (float*)take((size_t)NN * XD * 4);
    bf16* rrb  = (bf16*)take((size_t)NN * XD * 2);

    auto cdiv = [](int a, int b) { return (a + b - 1) / b; };

    // 1) convert feats + weights (transposed) to bf16
    for (int t = 0; t < 5; ++t)
        cvt_kernel<<<cdiv(NN * din[t], 256), 256, 0, stream>>>(feats[t], featb[t], NN * din[t]);
    for (int t = 0; t < 5; ++t)
        cvt_t_kernel<<<cdiv(din[t] * 128, 256), 256, 0, stream>>>(w1f[t], w1t[t], din[t], 128);
    for (int t = 0; t < 5; ++t)
        cvt_t_kernel<<<cdiv(128 * 128, 256), 256, 0, stream>>>(w2f[t], w2t[t], 128, 128);
    cvt_t_kernel<<<cdiv(640 * 1920, 256), 256, 0, stream>>>(w_xou, wxout, 640, 1920);
    cvt_t_kernel<<<cdiv(640 * 512, 256), 256, 0, stream>>>(w_o1, wo1t, 640, 512);

    // 2) five 2-layer MLPs -> x (bf16, [NN][640])
    for (int t = 0; t < 5; ++t)
        gemm_kernel<1><<<dim3(511, 2), 256, 0, stream>>>(featb[t], din[t], w1t[t], din[t], b1f[t],
                                                         hid1 + t * 128, XD);
    for (int t = 0; t < 5; ++t)
        gemm_kernel<1><<<dim3(511, 2), 256, 0, stream>>>(hid1 + t * 128, XD, w2t[t], 128, b2f[t],
                                                         xbf + t * 128, XD);

    // 3) xou GEMM + fused gates: writes ff (f32), rr (bf16), c0=(1-ff)*xx -> c
    xou_kernel<<<dim3(511, 10), 256, 0, stream>>>(xbf, wxout, b_xou, ffb, rrb, cc);

    // 4) tree recursion levels 1..8
    for (int n = 1; n <= 8; ++n) {
        int cnt = 1 << (8 - n);
        level_kernel<<<(NT * cnt * XD) / 256, 256, 0, stream>>>(cc, ffb, cnt);
    }

    // 5) h for all nodes (bf16, into hid1's region)
    bf16* hbf = hid1;
    h_kernel<<<cdiv(NN * XD, 256), 256, 0, stream>>>(cc, rrb, xbf, hbf);

    // 6) readout: hid2 = relu(h @ w_o1 + b_o1)  (into xbf's region), then out
    bf16* hid2 = xbf;
    gemm_kernel<1><<<dim3(511, 8), 256, 0, stream>>>(hbf, XD, wo1t, XD, b_o1, hid2, 512);
    out_kernel<<<NN / 4, 256, 0, stream>>>(hid2, w_o2, b_o2, outp);
}

// Round 2
// 430.516 us; speedup vs baseline: 1.9278x; 1.9278x over previous
//
#include <hip/hip_runtime.h>
#include <hip/hip_bf16.h>

typedef __hip_bfloat16 bf16;
typedef __attribute__((ext_vector_type(8))) short bfrag8;  // 8 bf16 = 4 VGPRs
typedef __attribute__((ext_vector_type(4))) float f4;

#define NN 32704      // total nodes = 64 trees * 511
#define MP 32768      // M padded to 128-multiple
#define PT 511
#define NT 64
#define XD 640

__device__ __forceinline__ float sigmoidf_(float x) { return 1.0f / (1.0f + expf(-x)); }

// async global->LDS, 16B per lane. LDS dest must be linear (wave base + lane*16);
// swizzle is applied on the GLOBAL source address (m173 pattern) + on ds_read.
__device__ __forceinline__ void gload16(const bf16* g, char* l) {
    __builtin_amdgcn_global_load_lds(
        (const __attribute__((address_space(1))) unsigned int*)(g),
        (__attribute__((address_space(3))) unsigned int*)(l), 16, 0, 0);
}

union bfu8 { bfrag8 v; bf16 h[8]; };

// ---------------- converts (vectorized, G13) ----------------
// src [nrows][din] f32 -> dst [MP][kpad] bf16, zero-padded rows/cols
__global__ void cvt_pad_kernel(const float* __restrict__ src, bf16* __restrict__ dst,
                               int nrows, int din, int kpad) {
    int g8 = kpad >> 3;
    int i = blockIdx.x * 256 + threadIdx.x;
    if (i >= MP * g8) return;
    int row = i / g8, c0 = (i - row * g8) * 8;
    bfu8 u; u.v = (bfrag8){0,0,0,0,0,0,0,0};
    if (row < nrows && c0 < din) {
        const float* s = src + (size_t)row * din + c0;
        float4 x = *(const float4*)s, y = *(const float4*)(s + 4);
        u.h[0] = __float2bfloat16(x.x); u.h[1] = __float2bfloat16(x.y);
        u.h[2] = __float2bfloat16(x.z); u.h[3] = __float2bfloat16(x.w);
        u.h[4] = __float2bfloat16(y.x); u.h[5] = __float2bfloat16(y.y);
        u.h[6] = __float2bfloat16(y.z); u.h[7] = __float2bfloat16(y.w);
    }
    *(bfrag8*)(dst + (size_t)i * 8) = u.v;
}

// src [K][Nc] f32 -> dst [Nc][kpad] bf16 (transposed weights, zero k-pad)
__global__ void cvt_t_pad_kernel(const float* __restrict__ src, bf16* __restrict__ dst,
                                 int K, int Nc, int kpad) {
    int g8 = kpad >> 3;
    int i = blockIdx.x * 256 + threadIdx.x;
    if (i >= Nc * g8) return;
    int n = i / g8, k0 = (i - n * g8) * 8;
    bfu8 u;
    bool val = k0 < K;  // K % 8 == 0 for all our weights
#pragma unroll
    for (int j = 0; j < 8; ++j)
        u.h[j] = val ? __float2bfloat16(src[(size_t)(k0 + j) * Nc + n]) : __float2bfloat16(0.0f);
    *(bfrag8*)(dst + (size_t)i * 8) = u.v;
}

// ---------------- generic LDS-staged GEMM (m97 structure + T2 swizzle) ----------------
// C[MP][ldc](+bias,relu) = A[MP][lda] @ Bt[N][ldb]^T, tiles 128x128, BK=64.
// grid (MP/128, N/128), block 256 = 4 waves in 2x2, each wave 64x64 (4x4 frags).
template <int ACT>
__global__ __launch_bounds__(256) void gemm_lds_kernel(
    const bf16* __restrict__ A, int lda,
    const bf16* __restrict__ Bt, int ldb, int K,
    const float* __restrict__ bias,
    bf16* __restrict__ C, int ldc)
{
    __shared__ char smem[32 * 1024];
    char* As = smem;           // [128 rows][128 B]
    char* Bs = smem + 16384;   // [128 rows][128 B]

    int tid = threadIdx.x;
    int lane = tid & 63, w = tid >> 6;
    int brow = blockIdx.x * 128, bcol = blockIdx.y * 128;
    int wr = (w >> 1) * 64, wc = (w & 1) * 64;
    int am = lane & 15, ah = lane >> 4;

    f4 acc[4][4] = {};

    for (int k0 = 0; k0 < K; k0 += 64) {
#pragma unroll
        for (int r = 0; r < 4; ++r) {
            int o = r * 4096 + tid * 16;            // linear LDS byte
            int row = o >> 7;
            int cb = (o & 127) ^ ((row & 7) << 4);  // inverse-swizzled source col
            gload16(A + (size_t)(brow + row) * lda + k0 + (cb >> 1), As + o);
            gload16(Bt + (size_t)(bcol + row) * ldb + k0 + (cb >> 1), Bs + o);
        }
        __syncthreads();
#pragma unroll
        for (int s = 0; s < 2; ++s) {
            int cb = s * 64 + ah * 16;
            bfrag8 a[4], b[4];
#pragma unroll
            for (int f = 0; f < 4; ++f) {
                int ra = wr + f * 16 + am;
                a[f] = *(const bfrag8*)(As + ra * 128 + (cb ^ ((ra & 7) << 4)));
                int rb = wc + f * 16 + am;
                b[f] = *(const bfrag8*)(Bs + rb * 128 + (cb ^ ((rb & 7) << 4)));
            }
#pragma unroll
            for (int i = 0; i < 4; ++i)
#pragma unroll
                for (int j = 0; j < 4; ++j)
                    acc[i][j] = __builtin_amdgcn_mfma_f32_16x16x32_bf16(a[i], b[j], acc[i][j], 0, 0, 0);
        }
        __syncthreads();
    }

#pragma unroll
    for (int i = 0; i < 4; ++i)
#pragma unroll
        for (int j = 0; j < 4; ++j)
#pragma unroll
            for (int r = 0; r < 4; ++r) {
                int row = brow + wr + i * 16 + ah * 4 + r;
                int col = bcol + wc + j * 16 + am;
                float v = acc[i][j][r] + bias[col];
                if (ACT) v = fmaxf(v, 0.0f);
                C[(size_t)row * ldc + col] = __float2bfloat16(v);
            }
}

// ---------------- xou GEMM, LDS-staged, fused gate epilogue ----------------
// Tile: 128 rows x 64 cols x 3 regions (xx/ff/rr share the A tile).
// grid (MP/128, 640/64), block 256 (4 waves 2x2; wave = 64 rows x 32 cols x 3).
__global__ __launch_bounds__(256) void xou_lds_kernel(
    const bf16* __restrict__ X,    // [MP][640]
    const bf16* __restrict__ Wt,   // [1920][640]
    const float* __restrict__ bias,
    float* __restrict__ ffp,       // [MP][640] f32
    bf16* __restrict__ rrp,        // [MP][640] bf16
    float* __restrict__ cc)        // [NN][640] f32 (d_out region)
{
    __shared__ char smem[40 * 1024];
    char* As = smem;           // [128][128B]
    char* Bs = smem + 16384;   // 3 x [64][128B]

    int tid = threadIdx.x;
    int lane = tid & 63, w = tid >> 6;
    int brow = blockIdx.x * 128, bcol = blockIdx.y * 64;
    int wr = (w >> 1) * 64, wc = (w & 1) * 32;
    int am = lane & 15, ah = lane >> 4;

    f4 acc[3][4][2] = {};

    for (int k0 = 0; k0 < 640; k0 += 64) {
#pragma unroll
        for (int r = 0; r < 4; ++r) {
            int o = r * 4096 + tid * 16;
            int row = o >> 7;
            int cb = (o & 127) ^ ((row & 7) << 4);
            gload16(X + (size_t)(brow + row) * XD + k0 + (cb >> 1), As + o);
        }
#pragma unroll
        for (int r = 0; r < 6; ++r) {
            int o = r * 4096 + tid * 16;            // within 24KB B area
            int row = o >> 7;                        // 0..191 over 3 regions
            int q = row >> 6, rl = row & 63;
            int cb = (o & 127) ^ ((row & 7) << 4);
            gload16(Wt + (size_t)(q * 640 + bcol + rl) * XD + k0 + (cb >> 1), Bs + o);
        }
        __syncthreads();
#pragma unroll
        for (int s = 0; s < 2; ++s) {
            int cb = s * 64 + ah * 16;
            bfrag8 a[4], b[3][2];
#pragma unroll
            for (int f = 0; f < 4; ++f) {
                int ra = wr + f * 16 + am;
                a[f] = *(const bfrag8*)(As + ra * 128 + (cb ^ ((ra & 7) << 4)));
            }
#pragma unroll
            for (int q = 0; q < 3; ++q)
#pragma unroll
                for (int f = 0; f < 2; ++f) {
                    int rb = wc + f * 16 + am;
                    b[q][f] = *(const bfrag8*)(Bs + q * 8192 + rb * 128 + (cb ^ ((rb & 7) << 4)));
                }
#pragma unroll
            for (int q = 0; q < 3; ++q)
#pragma unroll
                for (int i = 0; i < 4; ++i)
#pragma unroll
                    for (int j = 0; j < 2; ++j)
                        acc[q][i][j] = __builtin_amdgcn_mfma_f32_16x16x32_bf16(a[i], b[q][j], acc[q][i][j], 0, 0, 0);
        }
        __syncthreads();
    }

#pragma unroll
    for (int i = 0; i < 4; ++i)
#pragma unroll
        for (int j = 0; j < 2; ++j)
#pragma unroll
            for (int r = 0; r < 4; ++r) {
                int row = brow + wr + i * 16 + ah * 4 + r;
                int col = bcol + wc + j * 16 + am;
                size_t o = (size_t)row * XD + col;
                float xx = acc[0][i][j][r] + bias[col];
                float fv = sigmoidf_(acc[1][i][j][r] + bias[640 + col]);
                float rv = sigmoidf_(acc[2][i][j][r] + bias[1280 + col]);
                ffp[o] = fv;
                rrp[o] = __float2bfloat16(rv);
                if (row < NN) cc[o] = (1.0f - fv) * xx;
            }
}

// ---------------- tree recursion: ONE launch, block = (tree, 64-dim chunk) ----------------
// per level: c[p] = ff[p]*(c[2p+1]+c[2p+2]) + c[p]  (c[p] holds (1-ff)*xx)
__global__ __launch_bounds__(256) void levels_kernel(float* __restrict__ c,
                                                     const float* __restrict__ ff) {
    int t = blockIdx.x;
    int d0 = blockIdx.y * 64;
    size_t tb = (size_t)t * PT;
    for (int n = 1; n <= 8; ++n) {
        int cnt = 1 << (8 - n);
        int items = cnt * 16;  // float4 granules
        for (int it = threadIdx.x; it < items; it += 256) {
            int pl = (cnt - 1) + (it >> 4);
            int dq = d0 + (it & 15) * 4;
            size_t go = (tb + pl) * XD + dq;
            size_t co = (tb + 2 * pl + 1) * XD + dq;
            float4 l = *(const float4*)(c + co);
            float4 rg = *(const float4*)(c + co + XD);
            float4 f = *(const float4*)(ff + go);
            float4 cv = *(const float4*)(c + go);
            cv.x += f.x * (l.x + rg.x);
            cv.y += f.y * (l.y + rg.y);
            cv.z += f.z * (l.z + rg.z);
            cv.w += f.w * (l.w + rg.w);
            *(float4*)(c + go) = cv;
        }
        __threadfence_block();
        __syncthreads();
    }
}

// ---------------- h = rr*tanh(c) + (1-rr)*x, vectorized x8 ----------------
__global__ void h_kernel(const float* __restrict__ c, const bf16* __restrict__ rr,
                         const bf16* __restrict__ x, bf16* __restrict__ h) {
    size_t i = (size_t)blockIdx.x * 256 + threadIdx.x;  // short8 index
    const float4* cp = (const float4*)(c + i * 8);
    float4 c0 = cp[0], c1 = cp[1];
    bfu8 rv, xv, o;
    rv.v = *(const bfrag8*)(rr + i * 8);
    xv.v = *(const bfrag8*)(x + i * 8);
    float cv[8] = {c0.x, c0.y, c0.z, c0.w, c1.x, c1.y, c1.z, c1.w};
#pragma unroll
    for (int j = 0; j < 8; ++j) {
        float r = __bfloat162float(rv.h[j]);
        float xx = __bfloat162float(xv.h[j]);
        o.h[j] = __float2bfloat16(r * tanhf(cv[j]) + (1.0f - r) * xx);
    }
    *(bfrag8*)(h + i * 8) = o.v;
}

// ---------------- out = sigmoid(hid2 . w_o2 + b_o2), one wave per row ----------------
__global__ __launch_bounds__(256) void out_kernel(const bf16* __restrict__ h2,
                                                  const float* __restrict__ w2,
                                                  const float* __restrict__ b2,
                                                  float* __restrict__ out) {
    int lane = threadIdx.x & 63;
    int row = blockIdx.x * 4 + (threadIdx.x >> 6);
    bfu8 hv;
    hv.v = *(const bfrag8*)(h2 + (size_t)row * 512 + lane * 8);
    float s = 0.0f;
#pragma unroll
    for (int j = 0; j < 8; ++j)
        s += __bfloat162float(hv.h[j]) * w2[lane * 8 + j];
#pragma unroll
    for (int off = 32; off; off >>= 1) s += __shfl_down(s, off, 64);
    if (lane == 0) out[row] = 1.0f / (1.0f + expf(-(s + b2[0])));
}

// ---------------- host ----------------
extern "C" void kernel_launch(void* const* d_in, const int* in_sizes, int n_in,
                              void* d_out, int out_size, void* d_ws, size_t ws_size,
                              hipStream_t stream) {
    const int din[5]  = {32, 64, 256, 128, 16};
    const int kpad[5] = {64, 64, 256, 128, 64};

    const float* feats[5];
    const float *w1f[5], *b1f[5], *w2f[5], *b2f[5];
    for (int t = 0; t < 5; ++t) {
        feats[t] = (const float*)d_in[t];
        w1f[t] = (const float*)d_in[8 + 4 * t];
        b1f[t] = (const float*)d_in[9 + 4 * t];
        w2f[t] = (const float*)d_in[10 + 4 * t];
        b2f[t] = (const float*)d_in[11 + 4 * t];
    }
    const float* w_xou = (const float*)d_in[28];
    const float* b_xou = (const float*)d_in[29];
    const float* w_o1  = (const float*)d_in[30];
    const float* b_o1  = (const float*)d_in[31];
    const float* w_o2  = (const float*)d_in[32];
    const float* b_o2  = (const float*)d_in[33];

    float* outp = (float*)d_out;
    float* cc   = (float*)d_out + NN;

    char* ws = (char*)d_ws;
    size_t off = 0;
    auto take = [&](size_t bytes) -> char* {
        char* p = ws + off;
        off += (bytes + 255) & ~(size_t)255;
        return p;
    };
    bf16* w1t[5]; for (int t = 0; t < 5; ++t) w1t[t] = (bf16*)take((size_t)128 * kpad[t] * 2);
    bf16* w2t[5]; for (int t = 0; t < 5; ++t) w2t[t] = (bf16*)take((size_t)128 * 128 * 2);
    bf16* wxout = (bf16*)take((size_t)1920 * 640 * 2);
    bf16* wo1t  = (bf16*)take((size_t)512 * 640 * 2);
    bf16* featb[5]; for (int t = 0; t < 5; ++t) featb[t] = (bf16*)take((size_t)MP * kpad[t] * 2);
    bf16* hid1 = (bf16*)take((size_t)MP * XD * 2);   // later reused as h
    bf16* xbf  = (bf16*)take((size_t)MP * XD * 2);   // later reused as hid2 [MP][512]
    float* ffb = (float*)take((size_t)MP * XD * 4);
    bf16* rrb  = (bf16*)take((size_t)MP * XD * 2);

    auto cdiv = [](int a, int b) { return (a + b - 1) / b; };

    // 1) converts (vectorized)
    for (int t = 0; t < 5; ++t)
        cvt_pad_kernel<<<cdiv(MP * (kpad[t] >> 3), 256), 256, 0, stream>>>(
            feats[t], featb[t], NN, din[t], kpad[t]);
    for (int t = 0; t < 5; ++t)
        cvt_t_pad_kernel<<<cdiv(128 * (kpad[t] >> 3), 256), 256, 0, stream>>>(
            w1f[t], w1t[t], din[t], 128, kpad[t]);
    for (int t = 0; t < 5; ++t)
        cvt_t_pad_kernel<<<cdiv(128 * 16, 256), 256, 0, stream>>>(w2f[t], w2t[t], 128, 128, 128);
    cvt_t_pad_kernel<<<cdiv(1920 * 80, 256), 256, 0, stream>>>(w_xou, wxout, 640, 1920, 640);
    cvt_t_pad_kernel<<<cdiv(512 * 80, 256), 256, 0, stream>>>(w_o1, wo1t, 640, 512, 640);

    // 2) five 2-layer MLPs -> x
    for (int t = 0; t < 5; ++t)
        gemm_lds_kernel<1><<<dim3(MP / 128, 1), 256, 0, stream>>>(
            featb[t], kpad[t], w1t[t], kpad[t], kpad[t], b1f[t], hid1 + t * 128, XD);
    for (int t = 0; t < 5; ++t)
        gemm_lds_kernel<1><<<dim3(MP / 128, 1), 256, 0, stream>>>(
            hid1 + t * 128, XD, w2t[t], 128, 128, b2f[t], xbf + t * 128, XD);

    // 3) xou GEMM + fused gates
    xou_lds_kernel<<<dim3(MP / 128, 10), 256, 0, stream>>>(xbf, wxout, b_xou, ffb, rrb, cc);

    // 4) tree recursion (one launch)
    levels_kernel<<<dim3(NT, 10), 256, 0, stream>>>(cc, ffb);

    // 5) h for all real nodes
    bf16* hbf = hid1;
    h_kernel<<<(NN * XD) / (256 * 8), 256, 0, stream>>>(cc, rrb, xbf, hbf);

    // 6) readout
    bf16* hid2 = xbf;
    gemm_lds_kernel<1><<<dim3(MP / 128, 4), 256, 0, stream>>>(
        hbf, XD, wo1t, XD, 640, b_o1, hid2, 512);
    out_kernel<<<NN / 4, 256, 0, stream>>>(hid2, w_o2, b_o2, outp);
}

// Round 3
// 274.762 us; speedup vs baseline: 3.0206x; 1.5669x over previous
//
#include <hip/hip_runtime.h>
#include <hip/hip_bf16.h>

typedef __hip_bfloat16 bf16;
typedef __attribute__((ext_vector_type(8))) short bfrag8;  // 8 bf16 = 4 VGPRs
typedef __attribute__((ext_vector_type(4))) float f4;

#define NN 32704      // total nodes = 64 trees * 511
#define MP 32768      // M padded to 128-multiple
#define PT 511
#define NT 64
#define XD 640

union bfu8 { bfrag8 v; bf16 h[8]; };

__device__ __forceinline__ float fast_sigmoid(float x) {
    float e = exp2f(-1.44269504f * x);
    return __builtin_amdgcn_rcpf(1.0f + e);
}
__device__ __forceinline__ float fast_tanh(float x) {
    float e = exp2f(2.88539008f * x);          // x->+inf: e=inf, rcp=0 -> 1; x->-inf: e=0 -> -1
    return 1.0f - 2.0f * __builtin_amdgcn_rcpf(e + 1.0f);
}

// async global->LDS, 16B/lane. LDS dest linear; swizzle applied on GLOBAL source (m173).
__device__ __forceinline__ void gload16(const bf16* g, char* l) {
    __builtin_amdgcn_global_load_lds(
        (const __attribute__((address_space(1))) unsigned int*)(g),
        (__attribute__((address_space(3))) unsigned int*)(l), 16, 0, 0);
}

// ---------------- feat convert: all 5 types, one launch ----------------
struct FtArgs { const float* src[5]; bf16* dst[5]; int din[5]; int kpad[5]; };
__global__ __launch_bounds__(256) void feat_kernel(FtArgs a) {
    int t = blockIdx.y;
    int g8 = a.kpad[t] >> 3;
    int i = blockIdx.x * 256 + threadIdx.x;
    if (i >= MP * g8) return;
    int row = i / g8, c0 = (i - row * g8) * 8;
    bfu8 u; u.v = (bfrag8){0,0,0,0,0,0,0,0};
    int din = a.din[t];
    if (row < NN && c0 < din) {
        const float* s = a.src[t] + (size_t)row * din + c0;
        float4 x = *(const float4*)s, y = *(const float4*)(s + 4);
        u.h[0] = __float2bfloat16(x.x); u.h[1] = __float2bfloat16(x.y);
        u.h[2] = __float2bfloat16(x.z); u.h[3] = __float2bfloat16(x.w);
        u.h[4] = __float2bfloat16(y.x); u.h[5] = __float2bfloat16(y.y);
        u.h[6] = __float2bfloat16(y.z); u.h[7] = __float2bfloat16(y.w);
    }
    *(bfrag8*)(a.dst[t] + (size_t)i * 8) = u.v;
}

// ---------------- weight transpose-convert: all 12 weights, one launch ----------------
// src [K][Nc] f32 -> dst [Nc][kpad] bf16, 64x64 tiles via LDS (coalesced both sides).
struct WtSeg { const float* src; bf16* dst; int K, Nc, kpad, tile0; };
struct WtArgs { WtSeg s[12]; };
__global__ __launch_bounds__(256) void wt_kernel(WtArgs a) {
    int bid = blockIdx.x;
    int si = 0;
#pragma unroll
    for (int i = 1; i < 12; ++i) if (bid >= a.s[i].tile0) si = i;
    WtSeg sg = a.s[si];
    int local = bid - sg.tile0;
    int kt = sg.kpad >> 6;
    int nb = local / kt, kb = local - nb * kt;
    int n0 = nb * 64, k0 = kb * 64;

    __shared__ float T[64][65];
    int tid = threadIdx.x;
    int kk = tid >> 2, nq = (tid & 3) * 16;
    bool kval = (k0 + kk) < sg.K;
    const float* srow = sg.src + (size_t)(k0 + kk) * sg.Nc + n0 + nq;
#pragma unroll
    for (int c = 0; c < 4; ++c) {
        float4 v = kval ? *(const float4*)(srow + c * 4) : float4{0, 0, 0, 0};
        T[kk][nq + c * 4 + 0] = v.x; T[kk][nq + c * 4 + 1] = v.y;
        T[kk][nq + c * 4 + 2] = v.z; T[kk][nq + c * 4 + 3] = v.w;
    }
    __syncthreads();
    int n = tid >> 2;
#pragma unroll
    for (int c = 0; c < 2; ++c) {
        int k8 = (tid & 3) * 2 + c;
        bfu8 u;
#pragma unroll
        for (int j = 0; j < 8; ++j) u.h[j] = __float2bfloat16(T[k8 * 8 + j][n]);
        *(bfrag8*)(sg.dst + (size_t)(n0 + n) * sg.kpad + k0 + k8 * 8) = u.v;
    }
}

// ---------------- fused 2-layer MLP: hid1 stays in LDS ----------------
// grid (MP/128, 5), block 256. Per block: 128 rows x full 128 cols, both layers.
struct MlpP { const bf16* feat; const bf16* w1; const float* b1; const bf16* w2; const float* b2; };
struct MlpArgs { MlpP p[5]; };
__global__ __launch_bounds__(256) void mlp_kernel(MlpArgs args, bf16* __restrict__ out) {
    __shared__ __align__(16) char smem[64 * 1024];
    char* As = smem;            // [128][128B] feat k-slice
    char* Bs = smem + 16384;    // [128][128B] w1 k-slice
    char* Hs = smem + 32768;    // [128][256B] hid1 (bf16, swizzled)
    int t = blockIdx.y;
    int K = (t == 2) ? 256 : (t == 3) ? 128 : 64;   // kpad per type
    MlpP p = args.p[t];
    int tid = threadIdx.x, lane = tid & 63, w = tid >> 6;
    int brow = blockIdx.x * 128;
    int wr = (w >> 1) * 64, wc = (w & 1) * 64;
    int am = lane & 15, ah = lane >> 4;

    f4 acc[4][4] = {};
    for (int k0 = 0; k0 < K; k0 += 64) {
#pragma unroll
        for (int r = 0; r < 4; ++r) {
            int o = r * 4096 + tid * 16;
            int row = o >> 7;
            int cb = (o & 127) ^ ((row & 7) << 4);
            gload16(p.feat + (size_t)(brow + row) * K + k0 + (cb >> 1), As + o);
            gload16(p.w1 + (size_t)row * K + k0 + (cb >> 1), Bs + o);
        }
        __syncthreads();
#pragma unroll
        for (int s = 0; s < 2; ++s) {
            int cb = s * 64 + ah * 16;
            bfrag8 a[4], b[4];
#pragma unroll
            for (int f = 0; f < 4; ++f) {
                int ra = wr + f * 16 + am;
                a[f] = *(const bfrag8*)(As + ra * 128 + (cb ^ ((ra & 7) << 4)));
                int rb = wc + f * 16 + am;
                b[f] = *(const bfrag8*)(Bs + rb * 128 + (cb ^ ((rb & 7) << 4)));
            }
#pragma unroll
            for (int i = 0; i < 4; ++i)
#pragma unroll
                for (int j = 0; j < 4; ++j)
                    acc[i][j] = __builtin_amdgcn_mfma_f32_16x16x32_bf16(a[i], b[j], acc[i][j], 0, 0, 0);
        }
        __syncthreads();
    }
    // epilogue 1: relu -> Hs (swizzled 256B rows)
#pragma unroll
    for (int i = 0; i < 4; ++i)
#pragma unroll
        for (int j = 0; j < 4; ++j) {
            int col = wc + j * 16 + am;
            float bb = p.b1[col];
#pragma unroll
            for (int r = 0; r < 4; ++r) {
                int row = wr + i * 16 + ah * 4 + r;
                float v = fmaxf(acc[i][j][r] + bb, 0.0f);
                *(bf16*)(Hs + row * 256 + ((col * 2) ^ ((row & 7) << 4))) = __float2bfloat16(v);
            }
        }
    __syncthreads();
    // layer 2: A = Hs, B = w2 direct from global (L1-resident, 32KB)
    f4 acc2[4][4] = {};
#pragma unroll
    for (int ks = 0; ks < 4; ++ks) {
        bfrag8 a[4], b[4];
        int kb = ks * 64 + ah * 16;
#pragma unroll
        for (int f = 0; f < 4; ++f) {
            int ra = wr + f * 16 + am;
            a[f] = *(const bfrag8*)(Hs + ra * 256 + (kb ^ ((ra & 7) << 4)));
            int cbn = wc + f * 16 + am;
            b[f] = *(const bfrag8*)(p.w2 + (size_t)cbn * 128 + ks * 32 + ah * 8);
        }
#pragma unroll
        for (int i = 0; i < 4; ++i)
#pragma unroll
            for (int j = 0; j < 4; ++j)
                acc2[i][j] = __builtin_amdgcn_mfma_f32_16x16x32_bf16(a[i], b[j], acc2[i][j], 0, 0, 0);
    }
#pragma unroll
    for (int i = 0; i < 4; ++i)
#pragma unroll
        for (int j = 0; j < 4; ++j) {
            int col = wc + j * 16 + am;
            float bb = p.b2[col];
#pragma unroll
            for (int r = 0; r < 4; ++r) {
                int row = brow + wr + i * 16 + ah * 4 + r;
                float v = fmaxf(acc2[i][j][r] + bb, 0.0f);
                out[(size_t)row * XD + t * 128 + col] = __float2bfloat16(v);
            }
        }
}

// ---------------- xou GEMM: 2-phase dbuf + fused gate epilogue ----------------
// grid (MP/128, 10), block 256. Tile 128 rows x 64 cols x 3 regions.
__global__ __launch_bounds__(256) void xou_kernel(
    const bf16* __restrict__ X, const bf16* __restrict__ Wt,
    const float* __restrict__ bias,
    float* __restrict__ ffp, bf16* __restrict__ rrp, float* __restrict__ cc)
{
    __shared__ __align__(16) char smem[80 * 1024];   // 2 x (A 16K + B 24K)
    int tid = threadIdx.x, lane = tid & 63, w = tid >> 6;
    int brow = blockIdx.x * 128, bcol = blockIdx.y * 64;
    int wr = (w >> 1) * 64, wc = (w & 1) * 32;
    int am = lane & 15, ah = lane >> 4;

    auto stage = [&](int buf, int k0) {
        char* As = smem + buf * 40960;
        char* Bs = As + 16384;
#pragma unroll
        for (int r = 0; r < 4; ++r) {
            int o = r * 4096 + tid * 16;
            int row = o >> 7;
            int cb = (o & 127) ^ ((row & 7) << 4);
            gload16(X + (size_t)(brow + row) * XD + k0 + (cb >> 1), As + o);
        }
#pragma unroll
        for (int r = 0; r < 6; ++r) {
            int o = r * 4096 + tid * 16;
            int row = o >> 7;
            int q = row >> 6, rl = row & 63;
            int cb = (o & 127) ^ ((row & 7) << 4);
            gload16(Wt + (size_t)(q * 640 + bcol + rl) * XD + k0 + (cb >> 1), Bs + o);
        }
    };

    f4 acc[3][4][2] = {};
    stage(0, 0);
    __syncthreads();
    for (int kt = 0; kt < 10; ++kt) {
        int cur = kt & 1;
        if (kt < 9) stage(cur ^ 1, (kt + 1) * 64);   // issue next-tile loads FIRST (2-phase)
        char* As = smem + cur * 40960;
        char* Bs = As + 16384;
#pragma unroll
        for (int s = 0; s < 2; ++s) {
            int cb = s * 64 + ah * 16;
            bfrag8 a[4], b[3][2];
#pragma unroll
            for (int f = 0; f < 4; ++f) {
                int ra = wr + f * 16 + am;
                a[f] = *(const bfrag8*)(As + ra * 128 + (cb ^ ((ra & 7) << 4)));
            }
#pragma unroll
            for (int q = 0; q < 3; ++q)
#pragma unroll
                for (int f = 0; f < 2; ++f) {
                    int rb = wc + f * 16 + am;
                    b[q][f] = *(const bfrag8*)(Bs + q * 8192 + rb * 128 + (cb ^ ((rb & 7) << 4)));
                }
#pragma unroll
            for (int q = 0; q < 3; ++q)
#pragma unroll
                for (int i = 0; i < 4; ++i)
#pragma unroll
                    for (int j = 0; j < 2; ++j)
                        acc[q][i][j] = __builtin_amdgcn_mfma_f32_16x16x32_bf16(a[i], b[q][j], acc[q][i][j], 0, 0, 0);
        }
        __syncthreads();   // vmcnt(0) drain: covers the overlapped next-tile loads
    }

#pragma unroll
    for (int i = 0; i < 4; ++i)
#pragma unroll
        for (int j = 0; j < 2; ++j) {
            int col = bcol + wc + j * 16 + am;
            float bxx = bias[col], bff = bias[640 + col], brr = bias[1280 + col];
#pragma unroll
            for (int r = 0; r < 4; ++r) {
                int row = brow + wr + i * 16 + ah * 4 + r;
                size_t o = (size_t)row * XD + col;
                float xx = acc[0][i][j][r] + bxx;
                float fv = fast_sigmoid(acc[1][i][j][r] + bff);
                float rv = fast_sigmoid(acc[2][i][j][r] + brr);
                unsigned pl = (unsigned)row % 511u;   // node index within tree
                if (pl < 255u) ffp[o] = fv;           // ff only read for internal nodes
                rrp[o] = __float2bfloat16(rv);
                if (row < NN) cc[o] = (1.0f - fv) * xx;
            }
        }
}

// ---------------- tree recursion + h, one launch ----------------
__global__ __launch_bounds__(256) void levels_h_kernel(
    float* __restrict__ c, const float* __restrict__ ff,
    const bf16* __restrict__ rr, const bf16* __restrict__ x, bf16* __restrict__ h) {
    int t = blockIdx.x, d0 = blockIdx.y * 64;
    size_t tb = (size_t)t * PT;
    for (int n = 1; n <= 8; ++n) {
        int cnt = 1 << (8 - n);
        int items = cnt * 16;
        for (int it = threadIdx.x; it < items; it += 256) {
            int pl = (cnt - 1) + (it >> 4);
            int dq = d0 + (it & 15) * 4;
            size_t go = (tb + pl) * XD + dq;
            size_t co = (tb + 2 * pl + 1) * XD + dq;
            float4 l = *(const float4*)(c + co);
            float4 rg = *(const float4*)(c + co + XD);
            float4 f = *(const float4*)(ff + go);
            float4 cv = *(const float4*)(c + go);
            cv.x += f.x * (l.x + rg.x);
            cv.y += f.y * (l.y + rg.y);
            cv.z += f.z * (l.z + rg.z);
            cv.w += f.w * (l.w + rg.w);
            *(float4*)(c + go) = cv;
        }
        __threadfence_block();
        __syncthreads();
    }
    // h = rr*tanh(c) + (1-rr)*x for all 511 nodes, dims d0..d0+63
    for (int it = threadIdx.x; it < PT * 8; it += 256) {
        int node = it >> 3, dq = (it & 7) * 8;
        size_t o = (tb + node) * XD + d0 + dq;
        float4 c0 = *(const float4*)(c + o), c1 = *(const float4*)(c + o + 4);
        bfu8 rv, xv, ov;
        rv.v = *(const bfrag8*)(rr + o);
        xv.v = *(const bfrag8*)(x + o);
        float cv[8] = {c0.x, c0.y, c0.z, c0.w, c1.x, c1.y, c1.z, c1.w};
#pragma unroll
        for (int j = 0; j < 8; ++j) {
            float r = __bfloat162float(rv.h[j]);
            float xb = __bfloat162float(xv.h[j]);
            ov.h[j] = __float2bfloat16(r * fast_tanh(cv[j]) + (1.0f - r) * xb);
        }
        *(bfrag8*)(h + o) = ov.v;
    }
}

// ---------------- o1 GEMM: 2-phase dbuf ----------------
// hid2[MP][512] = relu(h[MP][640] @ wo1t[512][640]^T + b), grid (MP/128, 4)
__global__ __launch_bounds__(256) void gemm_db_kernel(
    const bf16* __restrict__ A, const bf16* __restrict__ Bt,
    const float* __restrict__ bias, bf16* __restrict__ C)
{
    __shared__ __align__(16) char smem[64 * 1024];
    int tid = threadIdx.x, lane = tid & 63, w = tid >> 6;
    int brow = blockIdx.x * 128, bcol = blockIdx.y * 128;
    int wr = (w >> 1) * 64, wc = (w & 1) * 64;
    int am = lane & 15, ah = lane >> 4;

    auto stage = [&](int buf, int k0) {
        char* As = smem + buf * 32768;
        char* Bs = As + 16384;
#pragma unroll
        for (int r = 0; r < 4; ++r) {
            int o = r * 4096 + tid * 16;
            int row = o >> 7;
            int cb = (o & 127) ^ ((row & 7) << 4);
            gload16(A + (size_t)(brow + row) * XD + k0 + (cb >> 1), As + o);
            gload16(Bt + (size_t)(bcol + row) * XD + k0 + (cb >> 1), Bs + o);
        }
    };

    f4 acc[4][4] = {};
    stage(0, 0);
    __syncthreads();
    for (int kt = 0; kt < 10; ++kt) {
        int cur = kt & 1;
        if (kt < 9) stage(cur ^ 1, (kt + 1) * 64);
        char* As = smem + cur * 32768;
        char* Bs = As + 16384;
#pragma unroll
        for (int s = 0; s < 2; ++s) {
            int cb = s * 64 + ah * 16;
            bfrag8 a[4], b[4];
#pragma unroll
            for (int f = 0; f < 4; ++f) {
                int ra = wr + f * 16 + am;
                a[f] = *(const bfrag8*)(As + ra * 128 + (cb ^ ((ra & 7) << 4)));
                int rb = wc + f * 16 + am;
                b[f] = *(const bfrag8*)(Bs + rb * 128 + (cb ^ ((rb & 7) << 4)));
            }
#pragma unroll
            for (int i = 0; i < 4; ++i)
#pragma unroll
                for (int j = 0; j < 4; ++j)
                    acc[i][j] = __builtin_amdgcn_mfma_f32_16x16x32_bf16(a[i], b[j], acc[i][j], 0, 0, 0);
        }
        __syncthreads();
    }
#pragma unroll
    for (int i = 0; i < 4; ++i)
#pragma unroll
        for (int j = 0; j < 4; ++j) {
            int col = bcol + wc + j * 16 + am;
            float bb = bias[col];
#pragma unroll
            for (int r = 0; r < 4; ++r) {
                int row = brow + wr + i * 16 + ah * 4 + r;
                float v = fmaxf(acc[i][j][r] + bb, 0.0f);
                C[(size_t)row * 512 + col] = __float2bfloat16(v);
            }
        }
}

// ---------------- out = sigmoid(hid2 . w_o2 + b_o2) ----------------
__global__ __launch_bounds__(256) void out_kernel(const bf16* __restrict__ h2,
                                                  const float* __restrict__ w2,
                                                  const float* __restrict__ b2,
                                                  float* __restrict__ out) {
    int lane = threadIdx.x & 63;
    int row = blockIdx.x * 4 + (threadIdx.x >> 6);
    bfu8 hv;
    hv.v = *(const bfrag8*)(h2 + (size_t)row * 512 + lane * 8);
    float s = 0.0f;
#pragma unroll
    for (int j = 0; j < 8; ++j)
        s += __bfloat162float(hv.h[j]) * w2[lane * 8 + j];
#pragma unroll
    for (int off = 32; off; off >>= 1) s += __shfl_down(s, off, 64);
    if (lane == 0) out[row] = fast_sigmoid(s + b2[0]);
}

// ---------------- host ----------------
extern "C" void kernel_launch(void* const* d_in, const int* in_sizes, int n_in,
                              void* d_out, int out_size, void* d_ws, size_t ws_size,
                              hipStream_t stream) {
    const int din[5]  = {32, 64, 256, 128, 16};
    const int kpad[5] = {64, 64, 256, 128, 64};

    const float* feats[5];
    const float *w1f[5], *b1f[5], *w2f[5], *b2f[5];
    for (int t = 0; t < 5; ++t) {
        feats[t] = (const float*)d_in[t];
        w1f[t] = (const float*)d_in[8 + 4 * t];
        b1f[t] = (const float*)d_in[9 + 4 * t];
        w2f[t] = (const float*)d_in[10 + 4 * t];
        b2f[t] = (const float*)d_in[11 + 4 * t];
    }
    const float* w_xou = (const float*)d_in[28];
    const float* b_xou = (const float*)d_in[29];
    const float* w_o1  = (const float*)d_in[30];
    const float* b_o1  = (const float*)d_in[31];
    const float* w_o2  = (const float*)d_in[32];
    const float* b_o2  = (const float*)d_in[33];

    float* outp = (float*)d_out;
    float* cc   = (float*)d_out + NN;

    char* ws = (char*)d_ws;
    size_t off = 0;
    auto take = [&](size_t bytes) -> char* {
        char* p = ws + off;
        off += (bytes + 255) & ~(size_t)255;
        return p;
    };
    bf16* w1t[5]; for (int t = 0; t < 5; ++t) w1t[t] = (bf16*)take((size_t)128 * kpad[t] * 2);
    bf16* w2t[5]; for (int t = 0; t < 5; ++t) w2t[t] = (bf16*)take((size_t)128 * 128 * 2);
    bf16* wxout = (bf16*)take((size_t)1920 * 640 * 2);
    bf16* wo1t  = (bf16*)take((size_t)512 * 640 * 2);
    bf16* featb[5]; for (int t = 0; t < 5; ++t) featb[t] = (bf16*)take((size_t)MP * kpad[t] * 2);
    bf16* hbf  = (bf16*)take((size_t)MP * XD * 2);
    bf16* xbf  = (bf16*)take((size_t)MP * XD * 2);   // x, later reused as hid2 [MP][512]
    float* ffb = (float*)take((size_t)MP * XD * 4);
    bf16* rrb  = (bf16*)take((size_t)MP * XD * 2);

    // 1) feat converts (one launch)
    FtArgs fa;
    for (int t = 0; t < 5; ++t) { fa.src[t] = feats[t]; fa.dst[t] = featb[t]; fa.din[t] = din[t]; fa.kpad[t] = kpad[t]; }
    feat_kernel<<<dim3(4096, 5), 256, 0, stream>>>(fa);

    // 2) weight transpose-converts (one launch)
    WtArgs wa;
    int t0 = 0, si = 0;
    auto addseg = [&](const float* s, bf16* d, int K, int Nc, int kp) {
        wa.s[si++] = {s, d, K, Nc, kp, t0};
        t0 += (Nc / 64) * (kp / 64);
    };
    for (int t = 0; t < 5; ++t) addseg(w1f[t], w1t[t], din[t], 128, kpad[t]);
    for (int t = 0; t < 5; ++t) addseg(w2f[t], w2t[t], 128, 128, 128);
    addseg(w_xou, wxout, 640, 1920, 640);
    addseg(w_o1, wo1t, 640, 512, 640);
    wt_kernel<<<t0, 256, 0, stream>>>(wa);   // t0 == 418

    // 3) fused MLPs -> x (one launch)
    MlpArgs ma;
    for (int t = 0; t < 5; ++t) ma.p[t] = {featb[t], w1t[t], b1f[t], w2t[t], b2f[t]};
    mlp_kernel<<<dim3(MP / 128, 5), 256, 0, stream>>>(ma, xbf);

    // 4) xou GEMM + fused gates
    xou_kernel<<<dim3(MP / 128, 10), 256, 0, stream>>>(xbf, wxout, b_xou, ffb, rrb, cc);

    // 5) tree recursion + h
    levels_h_kernel<<<dim3(NT, 10), 256, 0, stream>>>(cc, ffb, rrb, xbf, hbf);

    // 6) readout
    bf16* hid2 = xbf;
    gemm_db_kernel<<<dim3(MP / 128, 4), 256, 0, stream>>>(hbf, wo1t, b_o1, hid2);
    out_kernel<<<NN / 4, 256, 0, stream>>>(hid2, w_o2, b_o2, outp);
}

// Round 4
// 256.596 us; speedup vs baseline: 3.2344x; 1.0708x over previous
//
#include <hip/hip_runtime.h>
#include <hip/hip_bf16.h>

typedef __hip_bfloat16 bf16;
typedef __attribute__((ext_vector_type(8))) short bfrag8;  // 8 bf16 = 4 VGPRs
typedef __attribute__((ext_vector_type(4))) float f4;

#define NN 32704      // total nodes = 64 trees * 511
#define MP 32768      // M padded to 128-multiple
#define PT 511
#define NT 64
#define XD 640

union bfu8 { bfrag8 v; bf16 h[8]; };

__device__ __forceinline__ float fast_sigmoid(float x) {
    float e = exp2f(-1.44269504f * x);
    return __builtin_amdgcn_rcpf(1.0f + e);
}
__device__ __forceinline__ float fast_tanh(float x) {
    float e = exp2f(2.88539008f * x);
    return 1.0f - 2.0f * __builtin_amdgcn_rcpf(e + 1.0f);
}

// async global->LDS, 16B/lane. LDS dest linear; swizzle applied on GLOBAL source (m173).
__device__ __forceinline__ void gload16(const bf16* g, char* l) {
    __builtin_amdgcn_global_load_lds(
        (const __attribute__((address_space(1))) unsigned int*)(g),
        (__attribute__((address_space(3))) unsigned int*)(l), 16, 0, 0);
}

// ---------------- weight transpose-convert: all 12 weights, one launch ----------------
struct WtSeg { const float* src; bf16* dst; int K, Nc, kpad, tile0; };
struct WtArgs { WtSeg s[12]; };
__global__ __launch_bounds__(256) void wt_kernel(WtArgs a) {
    int bid = blockIdx.x;
    int si = 0;
#pragma unroll
    for (int i = 1; i < 12; ++i) if (bid >= a.s[i].tile0) si = i;
    WtSeg sg = a.s[si];
    int local = bid - sg.tile0;
    int kt = sg.kpad >> 6;
    int nb = local / kt, kb = local - nb * kt;
    int n0 = nb * 64, k0 = kb * 64;

    __shared__ float T[64][65];
    int tid = threadIdx.x;
    int kk = tid >> 2, nq = (tid & 3) * 16;
    bool kval = (k0 + kk) < sg.K;
    const float* srow = sg.src + (size_t)(k0 + kk) * sg.Nc + n0 + nq;
#pragma unroll
    for (int c = 0; c < 4; ++c) {
        float4 v = kval ? *(const float4*)(srow + c * 4) : float4{0, 0, 0, 0};
        T[kk][nq + c * 4 + 0] = v.x; T[kk][nq + c * 4 + 1] = v.y;
        T[kk][nq + c * 4 + 2] = v.z; T[kk][nq + c * 4 + 3] = v.w;
    }
    __syncthreads();
    int n = tid >> 2;
#pragma unroll
    for (int c = 0; c < 2; ++c) {
        int k8 = (tid & 3) * 2 + c;
        bfu8 u;
#pragma unroll
        for (int j = 0; j < 8; ++j) u.h[j] = __float2bfloat16(T[k8 * 8 + j][n]);
        *(bfrag8*)(sg.dst + (size_t)(n0 + n) * sg.kpad + k0 + k8 * 8) = u.v;
    }
}

// ---------------- fused MLP: f32-feat inline convert + 2 layers, hid1 in LDS ----------------
struct MlpP { const float* feat; const bf16* w1; const float* b1; const bf16* w2; const float* b2; };
struct MlpArgs { MlpP p[5]; int din[5]; int kpad[5]; };
__global__ __launch_bounds__(256) void mlp_kernel(MlpArgs args, bf16* __restrict__ out) {
    __shared__ __align__(16) char smem[64 * 1024];
    char* As = smem;            // [128][128B] feat k-tile (bf16, swizzled)
    char* Bs = smem + 16384;    // [128][128B] w1 k-tile
    char* Hs = smem + 32768;    // [128][256B] hid1 (bf16, swizzled)
    int t = blockIdx.y;
    int K = args.kpad[t], din = args.din[t];
    MlpP p = args.p[t];
    int tid = threadIdx.x, lane = tid & 63, w = tid >> 6;
    int brow = blockIdx.x * 128;
    int wr = (w >> 1) * 64, wc = (w & 1) * 64;
    int am = lane & 15, ah = lane >> 4;

    f4 acc[4][4] = {};
    for (int k0 = 0; k0 < K; k0 += 64) {
        // B: w1 k-tile via async LDS (inverse-swizzled source)
#pragma unroll
        for (int r = 0; r < 4; ++r) {
            int o = r * 4096 + tid * 16;
            int row = o >> 7;
            int cb = (o & 127) ^ ((row & 7) << 4);
            gload16(p.w1 + (size_t)row * K + k0 + (cb >> 1), Bs + o);
        }
        // A: f32 feats -> bf16 -> swizzled ds_write (reg-staged; fuses the convert kernel)
        {
            int col0 = (tid & 7) * 8;
#pragma unroll
            for (int c = 0; c < 4; ++c) {
                int row = (tid >> 3) + c * 32;
                int grow = brow + row;
                bfu8 u; u.v = (bfrag8){0,0,0,0,0,0,0,0};
                int kc = k0 + col0;
                if (grow < NN && kc < din) {
                    const float* s = p.feat + (size_t)grow * din + kc;
                    float4 x = *(const float4*)s, y = *(const float4*)(s + 4);
                    u.h[0] = __float2bfloat16(x.x); u.h[1] = __float2bfloat16(x.y);
                    u.h[2] = __float2bfloat16(x.z); u.h[3] = __float2bfloat16(x.w);
                    u.h[4] = __float2bfloat16(y.x); u.h[5] = __float2bfloat16(y.y);
                    u.h[6] = __float2bfloat16(y.z); u.h[7] = __float2bfloat16(y.w);
                }
                *(bfrag8*)(As + row * 128 + ((col0 * 2) ^ ((row & 7) << 4))) = u.v;
            }
        }
        __syncthreads();
#pragma unroll
        for (int s = 0; s < 2; ++s) {
            int cb = s * 64 + ah * 16;
            bfrag8 a[4], b[4];
#pragma unroll
            for (int f = 0; f < 4; ++f) {
                int ra = wr + f * 16 + am;
                a[f] = *(const bfrag8*)(As + ra * 128 + (cb ^ ((ra & 7) << 4)));
                int rb = wc + f * 16 + am;
                b[f] = *(const bfrag8*)(Bs + rb * 128 + (cb ^ ((rb & 7) << 4)));
            }
#pragma unroll
            for (int i = 0; i < 4; ++i)
#pragma unroll
                for (int j = 0; j < 4; ++j)
                    acc[i][j] = __builtin_amdgcn_mfma_f32_16x16x32_bf16(a[i], b[j], acc[i][j], 0, 0, 0);
        }
        __syncthreads();
    }
    // epilogue 1: relu -> Hs
#pragma unroll
    for (int i = 0; i < 4; ++i)
#pragma unroll
        for (int j = 0; j < 4; ++j) {
            int col = wc + j * 16 + am;
            float bb = p.b1[col];
#pragma unroll
            for (int r = 0; r < 4; ++r) {
                int row = wr + i * 16 + ah * 4 + r;
                float v = fmaxf(acc[i][j][r] + bb, 0.0f);
                *(bf16*)(Hs + row * 256 + ((col * 2) ^ ((row & 7) << 4))) = __float2bfloat16(v);
            }
        }
    __syncthreads();
    // layer 2: A = Hs, B = w2 direct from global (L1-resident, 32KB)
    f4 acc2[4][4] = {};
#pragma unroll
    for (int ks = 0; ks < 4; ++ks) {
        bfrag8 a[4], b[4];
        int kb = ks * 64 + ah * 16;
#pragma unroll
        for (int f = 0; f < 4; ++f) {
            int ra = wr + f * 16 + am;
            a[f] = *(const bfrag8*)(Hs + ra * 256 + (kb ^ ((ra & 7) << 4)));
            int cbn = wc + f * 16 + am;
            b[f] = *(const bfrag8*)(p.w2 + (size_t)cbn * 128 + ks * 32 + ah * 8);
        }
#pragma unroll
        for (int i = 0; i < 4; ++i)
#pragma unroll
            for (int j = 0; j < 4; ++j)
                acc2[i][j] = __builtin_amdgcn_mfma_f32_16x16x32_bf16(a[i], b[j], acc2[i][j], 0, 0, 0);
    }
#pragma unroll
    for (int i = 0; i < 4; ++i)
#pragma unroll
        for (int j = 0; j < 4; ++j) {
            int col = wc + j * 16 + am;
            float bb = p.b2[col];
#pragma unroll
            for (int r = 0; r < 4; ++r) {
                int row = brow + wr + i * 16 + ah * 4 + r;
                float v = fmaxf(acc2[i][j][r] + bb, 0.0f);
                out[(size_t)row * XD + t * 128 + col] = __float2bfloat16(v);
            }
        }
}

// ---------------- xou GEMM: counted-vmcnt pipeline (T4) + fused gate epilogue ----------------
// grid (10, MP/128): blockIdx.x = col-block (A-panel shared by consecutive blocks).
__global__ __launch_bounds__(256) void xou_kernel(
    const bf16* __restrict__ X, const bf16* __restrict__ Wt,
    const float* __restrict__ bias,
    float* __restrict__ ffp, bf16* __restrict__ rrp, float* __restrict__ cc)
{
    __shared__ __align__(16) char smem[80 * 1024];   // 2 x (A 16K + B 24K)
    int tid = threadIdx.x, lane = tid & 63, w = tid >> 6;
    int bcol = blockIdx.x * 64, brow = blockIdx.y * 128;
    int wr = (w >> 1) * 64, wc = (w & 1) * 32;
    int am = lane & 15, ah = lane >> 4;

    auto stage = [&](int buf, int k0) {   // 10 load instructions per wave
        char* As = smem + buf * 40960;
        char* Bs = As + 16384;
#pragma unroll
        for (int r = 0; r < 4; ++r) {
            int o = r * 4096 + tid * 16;
            int row = o >> 7;
            int cb = (o & 127) ^ ((row & 7) << 4);
            gload16(X + (size_t)(brow + row) * XD + k0 + (cb >> 1), As + o);
        }
#pragma unroll
        for (int r = 0; r < 6; ++r) {
            int o = r * 4096 + tid * 16;
            int row = o >> 7;
            int q = row >> 6, rl = row & 63;
            int cb = (o & 127) ^ ((row & 7) << 4);
            gload16(Wt + (size_t)(q * 640 + bcol + rl) * XD + k0 + (cb >> 1), Bs + o);
        }
    };

    f4 acc[3][4][2] = {};
    auto compute = [&](int buf) {
        char* As = smem + buf * 40960;
        char* Bs = As + 16384;
#pragma unroll
        for (int s = 0; s < 2; ++s) {
            int cb = s * 64 + ah * 16;
            bfrag8 a[4], b[3][2];
#pragma unroll
            for (int f = 0; f < 4; ++f) {
                int ra = wr + f * 16 + am;
                a[f] = *(const bfrag8*)(As + ra * 128 + (cb ^ ((ra & 7) << 4)));
            }
#pragma unroll
            for (int q = 0; q < 3; ++q)
#pragma unroll
                for (int f = 0; f < 2; ++f) {
                    int rb = wc + f * 16 + am;
                    b[q][f] = *(const bfrag8*)(Bs + q * 8192 + rb * 128 + (cb ^ ((rb & 7) << 4)));
                }
#pragma unroll
            for (int q = 0; q < 3; ++q)
#pragma unroll
                for (int i = 0; i < 4; ++i)
#pragma unroll
                    for (int j = 0; j < 2; ++j)
                        acc[q][i][j] = __builtin_amdgcn_mfma_f32_16x16x32_bf16(a[i], b[q][j], acc[q][i][j], 0, 0, 0);
        }
    };

    stage(0, 0);
    stage(1, 64);
    for (int kt = 0; kt < 8; ++kt) {
        asm volatile("s_waitcnt vmcnt(10)" ::: "memory");  // tile kt landed; kt+1 stays in flight
        __builtin_amdgcn_s_barrier();
        compute(kt & 1);
        __builtin_amdgcn_s_barrier();                      // all waves done reading before overwrite
        stage(kt & 1, (kt + 2) * 64);
    }
    asm volatile("s_waitcnt vmcnt(10)" ::: "memory");
    __builtin_amdgcn_s_barrier();
    compute(0);                                            // tile 8
    asm volatile("s_waitcnt vmcnt(0)" ::: "memory");
    __builtin_amdgcn_s_barrier();
    compute(1);                                            // tile 9

#pragma unroll
    for (int i = 0; i < 4; ++i)
#pragma unroll
        for (int j = 0; j < 2; ++j) {
            int col = bcol + wc + j * 16 + am;
            float bxx = bias[col], bff = bias[640 + col], brr = bias[1280 + col];
#pragma unroll
            for (int r = 0; r < 4; ++r) {
                int row = brow + wr + i * 16 + ah * 4 + r;
                size_t o = (size_t)row * XD + col;
                float xx = acc[0][i][j][r] + bxx;
                float fv = fast_sigmoid(acc[1][i][j][r] + bff);
                float rv = fast_sigmoid(acc[2][i][j][r] + brr);
                unsigned pl = (unsigned)row % 511u;
                if (pl < 255u) ffp[o] = fv;           // ff only read for internal nodes
                rrp[o] = __float2bfloat16(rv);
                if (row < NN) cc[o] = (1.0f - fv) * xx;
            }
        }
}

// ---------------- tree recursion + h, one launch ----------------
__global__ __launch_bounds__(256) void levels_h_kernel(
    float* __restrict__ c, const float* __restrict__ ff,
    const bf16* __restrict__ rr, const bf16* __restrict__ x, bf16* __restrict__ h) {
    int t = blockIdx.x, d0 = blockIdx.y * 64;
    size_t tb = (size_t)t * PT;
    for (int n = 1; n <= 8; ++n) {
        int cnt = 1 << (8 - n);
        int items = cnt * 16;
        for (int it = threadIdx.x; it < items; it += 256) {
            int pl = (cnt - 1) + (it >> 4);
            int dq = d0 + (it & 15) * 4;
            size_t go = (tb + pl) * XD + dq;
            size_t co = (tb + 2 * pl + 1) * XD + dq;
            float4 l = *(const float4*)(c + co);
            float4 rg = *(const float4*)(c + co + XD);
            float4 f = *(const float4*)(ff + go);
            float4 cv = *(const float4*)(c + go);
            cv.x += f.x * (l.x + rg.x);
            cv.y += f.y * (l.y + rg.y);
            cv.z += f.z * (l.z + rg.z);
            cv.w += f.w * (l.w + rg.w);
            *(float4*)(c + go) = cv;
        }
        __threadfence_block();
        __syncthreads();
    }
    for (int it = threadIdx.x; it < PT * 8; it += 256) {
        int node = it >> 3, dq = (it & 7) * 8;
        size_t o = (tb + node) * XD + d0 + dq;
        float4 c0 = *(const float4*)(c + o), c1 = *(const float4*)(c + o + 4);
        bfu8 rv, xv, ov;
        rv.v = *(const bfrag8*)(rr + o);
        xv.v = *(const bfrag8*)(x + o);
        float cv[8] = {c0.x, c0.y, c0.z, c0.w, c1.x, c1.y, c1.z, c1.w};
#pragma unroll
        for (int j = 0; j < 8; ++j) {
            float r = __bfloat162float(rv.h[j]);
            float xb = __bfloat162float(xv.h[j]);
            ov.h[j] = __float2bfloat16(r * fast_tanh(cv[j]) + (1.0f - r) * xb);
        }
        *(bfrag8*)(h + o) = ov.v;
    }
}

// ---------------- o1 GEMM: counted-vmcnt pipeline ----------------
// grid (4, MP/128): blockIdx.x = col-block.
__global__ __launch_bounds__(256) void gemm_db_kernel(
    const bf16* __restrict__ A, const bf16* __restrict__ Bt,
    const float* __restrict__ bias, bf16* __restrict__ C)
{
    __shared__ __align__(16) char smem[64 * 1024];
    int tid = threadIdx.x, lane = tid & 63, w = tid >> 6;
    int bcol = blockIdx.x * 128, brow = blockIdx.y * 128;
    int wr = (w >> 1) * 64, wc = (w & 1) * 64;
    int am = lane & 15, ah = lane >> 4;

    auto stage = [&](int buf, int k0) {   // 8 load instructions per wave
        char* As = smem + buf * 32768;
        char* Bs = As + 16384;
#pragma unroll
        for (int r = 0; r < 4; ++r) {
            int o = r * 4096 + tid * 16;
            int row = o >> 7;
            int cb = (o & 127) ^ ((row & 7) << 4);
            gload16(A + (size_t)(brow + row) * XD + k0 + (cb >> 1), As + o);
            gload16(Bt + (size_t)(bcol + row) * XD + k0 + (cb >> 1), Bs + o);
        }
    };

    f4 acc[4][4] = {};
    auto compute = [&](int buf) {
        char* As = smem + buf * 32768;
        char* Bs = As + 16384;
#pragma unroll
        for (int s = 0; s < 2; ++s) {
            int cb = s * 64 + ah * 16;
            bfrag8 a[4], b[4];
#pragma unroll
            for (int f = 0; f < 4; ++f) {
                int ra = wr + f * 16 + am;
                a[f] = *(const bfrag8*)(As + ra * 128 + (cb ^ ((ra & 7) << 4)));
                int rb = wc + f * 16 + am;
                b[f] = *(const bfrag8*)(Bs + rb * 128 + (cb ^ ((rb & 7) << 4)));
            }
#pragma unroll
            for (int i = 0; i < 4; ++i)
#pragma unroll
                for (int j = 0; j < 4; ++j)
                    acc[i][j] = __builtin_amdgcn_mfma_f32_16x16x32_bf16(a[i], b[j], acc[i][j], 0, 0, 0);
        }
    };

    stage(0, 0);
    stage(1, 64);
    for (int kt = 0; kt < 8; ++kt) {
        asm volatile("s_waitcnt vmcnt(8)" ::: "memory");
        __builtin_amdgcn_s_barrier();
        compute(kt & 1);
        __builtin_amdgcn_s_barrier();
        stage(kt & 1, (kt + 2) * 64);
    }
    asm volatile("s_waitcnt vmcnt(8)" ::: "memory");
    __builtin_amdgcn_s_barrier();
    compute(0);
    asm volatile("s_waitcnt vmcnt(0)" ::: "memory");
    __builtin_amdgcn_s_barrier();
    compute(1);

#pragma unroll
    for (int i = 0; i < 4; ++i)
#pragma unroll
        for (int j = 0; j < 4; ++j) {
            int col = bcol + wc + j * 16 + am;
            float bb = bias[col];
#pragma unroll
            for (int r = 0; r < 4; ++r) {
                int row = brow + wr + i * 16 + ah * 4 + r;
                float v = fmaxf(acc[i][j][r] + bb, 0.0f);
                C[(size_t)row * 512 + col] = __float2bfloat16(v);
            }
        }
}

// ---------------- out = sigmoid(hid2 . w_o2 + b_o2) ----------------
__global__ __launch_bounds__(256) void out_kernel(const bf16* __restrict__ h2,
                                                  const float* __restrict__ w2,
                                                  const float* __restrict__ b2,
                                                  float* __restrict__ out) {
    int lane = threadIdx.x & 63;
    int row = blockIdx.x * 4 + (threadIdx.x >> 6);
    bfu8 hv;
    hv.v = *(const bfrag8*)(h2 + (size_t)row * 512 + lane * 8);
    float s = 0.0f;
#pragma unroll
    for (int j = 0; j < 8; ++j)
        s += __bfloat162float(hv.h[j]) * w2[lane * 8 + j];
#pragma unroll
    for (int off = 32; off; off >>= 1) s += __shfl_down(s, off, 64);
    if (lane == 0) out[row] = fast_sigmoid(s + b2[0]);
}

// ---------------- host ----------------
extern "C" void kernel_launch(void* const* d_in, const int* in_sizes, int n_in,
                              void* d_out, int out_size, void* d_ws, size_t ws_size,
                              hipStream_t stream) {
    const int din[5]  = {32, 64, 256, 128, 16};
    const int kpad[5] = {64, 64, 256, 128, 64};

    const float* feats[5];
    const float *w1f[5], *b1f[5], *w2f[5], *b2f[5];
    for (int t = 0; t < 5; ++t) {
        feats[t] = (const float*)d_in[t];
        w1f[t] = (const float*)d_in[8 + 4 * t];
        b1f[t] = (const float*)d_in[9 + 4 * t];
        w2f[t] = (const float*)d_in[10 + 4 * t];
        b2f[t] = (const float*)d_in[11 + 4 * t];
    }
    const float* w_xou = (const float*)d_in[28];
    const float* b_xou = (const float*)d_in[29];
    const float* w_o1  = (const float*)d_in[30];
    const float* b_o1  = (const float*)d_in[31];
    const float* w_o2  = (const float*)d_in[32];
    const float* b_o2  = (const float*)d_in[33];

    float* outp = (float*)d_out;
    float* cc   = (float*)d_out + NN;

    char* ws = (char*)d_ws;
    size_t off = 0;
    auto take = [&](size_t bytes) -> char* {
        char* p = ws + off;
        off += (bytes + 255) & ~(size_t)255;
        return p;
    };
    bf16* w1t[5]; for (int t = 0; t < 5; ++t) w1t[t] = (bf16*)take((size_t)128 * kpad[t] * 2);
    bf16* w2t[5]; for (int t = 0; t < 5; ++t) w2t[t] = (bf16*)take((size_t)128 * 128 * 2);
    bf16* wxout = (bf16*)take((size_t)1920 * 640 * 2);
    bf16* wo1t  = (bf16*)take((size_t)512 * 640 * 2);
    bf16* hbf  = (bf16*)take((size_t)MP * XD * 2);
    bf16* xbf  = (bf16*)take((size_t)MP * XD * 2);   // x, later reused as hid2 [MP][512]
    float* ffb = (float*)take((size_t)MP * XD * 4);
    bf16* rrb  = (bf16*)take((size_t)MP * XD * 2);

    // 1) weight transpose-converts (one launch)
    WtArgs wa;
    int t0 = 0, si = 0;
    auto addseg = [&](const float* s, bf16* d, int K, int Nc, int kp) {
        wa.s[si++] = {s, d, K, Nc, kp, t0};
        t0 += (Nc / 64) * (kp / 64);
    };
    for (int t = 0; t < 5; ++t) addseg(w1f[t], w1t[t], din[t], 128, kpad[t]);
    for (int t = 0; t < 5; ++t) addseg(w2f[t], w2t[t], 128, 128, 128);
    addseg(w_xou, wxout, 640, 1920, 640);
    addseg(w_o1, wo1t, 640, 512, 640);
    wt_kernel<<<t0, 256, 0, stream>>>(wa);

    // 2) fused MLPs (f32 convert inline) -> x
    MlpArgs ma;
    for (int t = 0; t < 5; ++t) {
        ma.p[t] = {feats[t], w1t[t], b1f[t], w2t[t], b2f[t]};
        ma.din[t] = din[t]; ma.kpad[t] = kpad[t];
    }
    mlp_kernel<<<dim3(MP / 128, 5), 256, 0, stream>>>(ma, xbf);

    // 3) xou GEMM + fused gates (col-major grid for A reuse)
    xou_kernel<<<dim3(10, MP / 128), 256, 0, stream>>>(xbf, wxout, b_xou, ffb, rrb, cc);

    // 4) tree recursion + h
    levels_h_kernel<<<dim3(NT, 10), 256, 0, stream>>>(cc, ffb, rrb, xbf, hbf);

    // 5) readout
    bf16* hid2 = xbf;
    gemm_db_kernel<<<dim3(4, MP / 128), 256, 0, stream>>>(hbf, wo1t, b_o1, hid2);
    out_kernel<<<NN / 4, 256, 0, stream>>>(hid2, w_o2, b_o2, outp);
}

// Round 5
// 251.587 us; speedup vs baseline: 3.2988x; 1.0199x over previous
//
#include <hip/hip_runtime.h>
#include <hip/hip_bf16.h>

typedef __hip_bfloat16 bf16;
typedef __attribute__((ext_vector_type(8))) short bfrag8;  // 8 bf16 = 4 VGPRs
typedef __attribute__((ext_vector_type(4))) float f4;

#define NN 32704      // total nodes = 64 trees * 511
#define MP 32768      // M padded to 128-multiple
#define PT 511
#define NT 64
#define XD 640

union bfu8 { bfrag8 v; bf16 h[8]; };

__device__ __forceinline__ float fast_sigmoid(float x) {
    float e = exp2f(-1.44269504f * x);
    return __builtin_amdgcn_rcpf(1.0f + e);
}
__device__ __forceinline__ float fast_tanh(float x) {
    float e = exp2f(2.88539008f * x);
    return 1.0f - 2.0f * __builtin_amdgcn_rcpf(e + 1.0f);
}

// async global->LDS, 16B/lane. LDS dest linear; swizzle applied on GLOBAL source (m173).
__device__ __forceinline__ void gload16(const bf16* g, char* l) {
    __builtin_amdgcn_global_load_lds(
        (const __attribute__((address_space(1))) unsigned int*)(g),
        (__attribute__((address_space(3))) unsigned int*)(l), 16, 0, 0);
}

// ---------------- weight transpose-convert: all 12 weights, one launch ----------------
struct WtSeg { const float* src; bf16* dst; int K, Nc, kpad, tile0; };
struct WtArgs { WtSeg s[12]; };
__global__ __launch_bounds__(256) void wt_kernel(WtArgs a) {
    int bid = blockIdx.x;
    int si = 0;
#pragma unroll
    for (int i = 1; i < 12; ++i) if (bid >= a.s[i].tile0) si = i;
    WtSeg sg = a.s[si];
    int local = bid - sg.tile0;
    int kt = sg.kpad >> 6;
    int nb = local / kt, kb = local - nb * kt;
    int n0 = nb * 64, k0 = kb * 64;

    __shared__ float T[64][65];
    int tid = threadIdx.x;
    int kk = tid >> 2, nq = (tid & 3) * 16;
    bool kval = (k0 + kk) < sg.K;
    const float* srow = sg.src + (size_t)(k0 + kk) * sg.Nc + n0 + nq;
#pragma unroll
    for (int c = 0; c < 4; ++c) {
        float4 v = kval ? *(const float4*)(srow + c * 4) : float4{0, 0, 0, 0};
        T[kk][nq + c * 4 + 0] = v.x; T[kk][nq + c * 4 + 1] = v.y;
        T[kk][nq + c * 4 + 2] = v.z; T[kk][nq + c * 4 + 3] = v.w;
    }
    __syncthreads();
    int n = tid >> 2;
#pragma unroll
    for (int c = 0; c < 2; ++c) {
        int k8 = (tid & 3) * 2 + c;
        bfu8 u;
#pragma unroll
        for (int j = 0; j < 8; ++j) u.h[j] = __float2bfloat16(T[k8 * 8 + j][n]);
        *(bfrag8*)(sg.dst + (size_t)(n0 + n) * sg.kpad + k0 + k8 * 8) = u.v;
    }
}

// ---------------- fused MLP: f32-feat inline convert + 2 layers, hid1 in LDS ----------------
struct MlpP { const float* feat; const bf16* w1; const float* b1; const bf16* w2; const float* b2; };
struct MlpArgs { MlpP p[5]; int din[5]; int kpad[5]; };
__global__ __launch_bounds__(256) void mlp_kernel(MlpArgs args, bf16* __restrict__ out) {
    __shared__ __align__(16) char smem[64 * 1024];
    char* As = smem;            // [128][128B] feat k-tile (bf16, swizzled)
    char* Bs = smem + 16384;    // [128][128B] w1 k-tile
    char* Hs = smem + 32768;    // [128][256B] hid1 (bf16, swizzled)
    int t = blockIdx.y;
    int K = args.kpad[t], din = args.din[t];
    MlpP p = args.p[t];
    int tid = threadIdx.x, lane = tid & 63, w = tid >> 6;
    int brow = blockIdx.x * 128;
    int wr = (w >> 1) * 64, wc = (w & 1) * 64;
    int am = lane & 15, ah = lane >> 4;

    f4 acc[4][4] = {};
    for (int k0 = 0; k0 < K; k0 += 64) {
#pragma unroll
        for (int r = 0; r < 4; ++r) {
            int o = r * 4096 + tid * 16;
            int row = o >> 7;
            int cb = (o & 127) ^ ((row & 7) << 4);
            gload16(p.w1 + (size_t)row * K + k0 + (cb >> 1), Bs + o);
        }
        {
            int col0 = (tid & 7) * 8;
#pragma unroll
            for (int c = 0; c < 4; ++c) {
                int row = (tid >> 3) + c * 32;
                int grow = brow + row;
                bfu8 u; u.v = (bfrag8){0,0,0,0,0,0,0,0};
                int kc = k0 + col0;
                if (grow < NN && kc < din) {
                    const float* s = p.feat + (size_t)grow * din + kc;
                    float4 x = *(const float4*)s, y = *(const float4*)(s + 4);
                    u.h[0] = __float2bfloat16(x.x); u.h[1] = __float2bfloat16(x.y);
                    u.h[2] = __float2bfloat16(x.z); u.h[3] = __float2bfloat16(x.w);
                    u.h[4] = __float2bfloat16(y.x); u.h[5] = __float2bfloat16(y.y);
                    u.h[6] = __float2bfloat16(y.z); u.h[7] = __float2bfloat16(y.w);
                }
                *(bfrag8*)(As + row * 128 + ((col0 * 2) ^ ((row & 7) << 4))) = u.v;
            }
        }
        __syncthreads();
#pragma unroll
        for (int s = 0; s < 2; ++s) {
            int cb = s * 64 + ah * 16;
            bfrag8 a[4], b[4];
#pragma unroll
            for (int f = 0; f < 4; ++f) {
                int ra = wr + f * 16 + am;
                a[f] = *(const bfrag8*)(As + ra * 128 + (cb ^ ((ra & 7) << 4)));
                int rb = wc + f * 16 + am;
                b[f] = *(const bfrag8*)(Bs + rb * 128 + (cb ^ ((rb & 7) << 4)));
            }
#pragma unroll
            for (int i = 0; i < 4; ++i)
#pragma unroll
                for (int j = 0; j < 4; ++j)
                    acc[i][j] = __builtin_amdgcn_mfma_f32_16x16x32_bf16(a[i], b[j], acc[i][j], 0, 0, 0);
        }
        __syncthreads();
    }
#pragma unroll
    for (int i = 0; i < 4; ++i)
#pragma unroll
        for (int j = 0; j < 4; ++j) {
            int col = wc + j * 16 + am;
            float bb = p.b1[col];
#pragma unroll
            for (int r = 0; r < 4; ++r) {
                int row = wr + i * 16 + ah * 4 + r;
                float v = fmaxf(acc[i][j][r] + bb, 0.0f);
                *(bf16*)(Hs + row * 256 + ((col * 2) ^ ((row & 7) << 4))) = __float2bfloat16(v);
            }
        }
    __syncthreads();
    f4 acc2[4][4] = {};
#pragma unroll
    for (int ks = 0; ks < 4; ++ks) {
        bfrag8 a[4], b[4];
        int kb = ks * 64 + ah * 16;
#pragma unroll
        for (int f = 0; f < 4; ++f) {
            int ra = wr + f * 16 + am;
            a[f] = *(const bfrag8*)(Hs + ra * 256 + (kb ^ ((ra & 7) << 4)));
            int cbn = wc + f * 16 + am;
            b[f] = *(const bfrag8*)(p.w2 + (size_t)cbn * 128 + ks * 32 + ah * 8);
        }
#pragma unroll
        for (int i = 0; i < 4; ++i)
#pragma unroll
            for (int j = 0; j < 4; ++j)
                acc2[i][j] = __builtin_amdgcn_mfma_f32_16x16x32_bf16(a[i], b[j], acc2[i][j], 0, 0, 0);
    }
#pragma unroll
    for (int i = 0; i < 4; ++i)
#pragma unroll
        for (int j = 0; j < 4; ++j) {
            int col = wc + j * 16 + am;
            float bb = p.b2[col];
#pragma unroll
            for (int r = 0; r < 4; ++r) {
                int row = brow + wr + i * 16 + ah * 4 + r;
                float v = fmaxf(acc2[i][j][r] + bb, 0.0f);
                out[(size_t)row * XD + t * 128 + col] = __float2bfloat16(v);
            }
        }
}

// ---------------- xou GEMM: counted-vmcnt pipeline + T1 XCD swizzle ----------------
// 1D grid 2560 blocks; work id = XCD-contiguous chunks so the 10 col-blocks of a
// row-panel (and neighboring panels) share one XCD's L2 -> X fetched once from HBM.
__global__ __launch_bounds__(256) void xou_kernel(
    const bf16* __restrict__ X, const bf16* __restrict__ Wt,
    const float* __restrict__ bias,
    float* __restrict__ ffp, bf16* __restrict__ rrp, float* __restrict__ cc)
{
    __shared__ __align__(16) char smem[80 * 1024];   // 2 x (A 16K + B 24K)
    int bid = blockIdx.x;
    int swz = (bid & 7) * 320 + (bid >> 3);          // bijective, nwg=2560
    int bcol = (swz % 10) * 64;
    int brow = (swz / 10) * 128;
    int tid = threadIdx.x, lane = tid & 63, w = tid >> 6;
    int wr = (w >> 1) * 64, wc = (w & 1) * 32;
    int am = lane & 15, ah = lane >> 4;

    auto stage = [&](int buf, int k0) {   // 10 load instructions per wave
        char* As = smem + buf * 40960;
        char* Bs = As + 16384;
#pragma unroll
        for (int r = 0; r < 4; ++r) {
            int o = r * 4096 + tid * 16;
            int row = o >> 7;
            int cb = (o & 127) ^ ((row & 7) << 4);
            gload16(X + (size_t)(brow + row) * XD + k0 + (cb >> 1), As + o);
        }
#pragma unroll
        for (int r = 0; r < 6; ++r) {
            int o = r * 4096 + tid * 16;
            int row = o >> 7;
            int q = row >> 6, rl = row & 63;
            int cb = (o & 127) ^ ((row & 7) << 4);
            gload16(Wt + (size_t)(q * 640 + bcol + rl) * XD + k0 + (cb >> 1), Bs + o);
        }
    };

    f4 acc[3][4][2] = {};
    auto compute = [&](int buf) {
        char* As = smem + buf * 40960;
        char* Bs = As + 16384;
#pragma unroll
        for (int s = 0; s < 2; ++s) {
            int cb = s * 64 + ah * 16;
            bfrag8 a[4], b[3][2];
#pragma unroll
            for (int f = 0; f < 4; ++f) {
                int ra = wr + f * 16 + am;
                a[f] = *(const bfrag8*)(As + ra * 128 + (cb ^ ((ra & 7) << 4)));
            }
#pragma unroll
            for (int q = 0; q < 3; ++q)
#pragma unroll
                for (int f = 0; f < 2; ++f) {
                    int rb = wc + f * 16 + am;
                    b[q][f] = *(const bfrag8*)(Bs + q * 8192 + rb * 128 + (cb ^ ((rb & 7) << 4)));
                }
#pragma unroll
            for (int q = 0; q < 3; ++q)
#pragma unroll
                for (int i = 0; i < 4; ++i)
#pragma unroll
                    for (int j = 0; j < 2; ++j)
                        acc[q][i][j] = __builtin_amdgcn_mfma_f32_16x16x32_bf16(a[i], b[q][j], acc[q][i][j], 0, 0, 0);
        }
    };

    stage(0, 0);
    stage(1, 64);
    for (int kt = 0; kt < 8; ++kt) {
        asm volatile("s_waitcnt vmcnt(10)" ::: "memory");  // tile kt landed; kt+1 in flight
        __builtin_amdgcn_s_barrier();
        compute(kt & 1);
        __builtin_amdgcn_s_barrier();                      // all waves done reading before overwrite
        stage(kt & 1, (kt + 2) * 64);
    }
    asm volatile("s_waitcnt vmcnt(10)" ::: "memory");
    __builtin_amdgcn_s_barrier();
    compute(0);
    asm volatile("s_waitcnt vmcnt(0)" ::: "memory");
    __builtin_amdgcn_s_barrier();
    compute(1);

#pragma unroll
    for (int i = 0; i < 4; ++i)
#pragma unroll
        for (int j = 0; j < 2; ++j) {
            int col = bcol + wc + j * 16 + am;
            float bxx = bias[col], bff = bias[640 + col], brr = bias[1280 + col];
#pragma unroll
            for (int r = 0; r < 4; ++r) {
                int row = brow + wr + i * 16 + ah * 4 + r;
                size_t o = (size_t)row * XD + col;
                float xx = acc[0][i][j][r] + bxx;
                float fv = fast_sigmoid(acc[1][i][j][r] + bff);
                float rv = fast_sigmoid(acc[2][i][j][r] + brr);
                unsigned pl = (unsigned)row % 511u;
                if (pl < 255u) ffp[o] = fv;           // ff only read for internal nodes
                rrp[o] = __float2bfloat16(rv);
                if (row < NN) cc[o] = (1.0f - fv) * xx;
            }
        }
}

// ---------------- tree recursion in LDS + h, one launch ----------------
// block = (tree, 32-dim chunk). c[511][32] staged in LDS (XOR-swizzled float4
// granules -> 2 lanes/bank, conflict-free); all 8 levels run in LDS; internal c
// written back; h computed inline.
__device__ __forceinline__ int clidx(int node, int e) {   // element index into cl[]
    int g = e & ~3;
    return node * 32 + (g ^ ((node & 7) * 4)) + (e & 3);
}
__global__ __launch_bounds__(256) void levels_h_kernel(
    float* __restrict__ c, const float* __restrict__ ff,
    const bf16* __restrict__ rr, const bf16* __restrict__ x, bf16* __restrict__ h) {
    __shared__ __align__(16) float cl[511 * 32];   // 65,408 B
    int t = blockIdx.x, d0 = blockIdx.y * 32;
    size_t tb = (size_t)t * PT;
    int tid = threadIdx.x;

    // load all 511 rows x 32 dims
    for (int it = tid; it < 511 * 8; it += 256) {
        int node = it >> 3, q = (it & 7) * 4;
        *(float4*)&cl[clidx(node, q)] = *(const float4*)(c + (tb + node) * XD + d0 + q);
    }
    __syncthreads();

    for (int n = 1; n <= 8; ++n) {
        int cnt = 1 << (8 - n);
        for (int it = tid; it < cnt * 8; it += 256) {
            int pl = (cnt - 1) + (it >> 3), q = (it & 7) * 4;
            float4 f = *(const float4*)(ff + (tb + pl) * XD + d0 + q);
            float4 l  = *(const float4*)&cl[clidx(2 * pl + 1, q)];
            float4 rg = *(const float4*)&cl[clidx(2 * pl + 2, q)];
            float4 cv = *(const float4*)&cl[clidx(pl, q)];
            cv.x += f.x * (l.x + rg.x);
            cv.y += f.y * (l.y + rg.y);
            cv.z += f.z * (l.z + rg.z);
            cv.w += f.w * (l.w + rg.w);
            *(float4*)&cl[clidx(pl, q)] = cv;
        }
        __syncthreads();
    }

    // write back internal-node c
    for (int it = tid; it < 255 * 8; it += 256) {
        int pl = it >> 3, q = (it & 7) * 4;
        *(float4*)(c + (tb + pl) * XD + d0 + q) = *(const float4*)&cl[clidx(pl, q)];
    }
    // h = rr*tanh(c) + (1-rr)*x, all 511 nodes
    for (int it = tid; it < 511 * 4; it += 256) {
        int node = it >> 2, q = (it & 3) * 8;
        size_t o = (tb + node) * XD + d0 + q;
        bfu8 rv, xv, ov;
        rv.v = *(const bfrag8*)(rr + o);
        xv.v = *(const bfrag8*)(x + o);
        float4 c0 = *(const float4*)&cl[clidx(node, q)];
        float4 c1 = *(const float4*)&cl[clidx(node, q + 4)];
        float cv[8] = {c0.x, c0.y, c0.z, c0.w, c1.x, c1.y, c1.z, c1.w};
#pragma unroll
        for (int j = 0; j < 8; ++j) {
            float r = __bfloat162float(rv.h[j]);
            float xb = __bfloat162float(xv.h[j]);
            ov.h[j] = __float2bfloat16(r * fast_tanh(cv[j]) + (1.0f - r) * xb);
        }
        *(bfrag8*)(h + o) = ov.v;
    }
}

// ---------------- o1 GEMM: counted-vmcnt pipeline + T1 XCD swizzle ----------------
__global__ __launch_bounds__(256) void gemm_db_kernel(
    const bf16* __restrict__ A, const bf16* __restrict__ Bt,
    const float* __restrict__ bias, bf16* __restrict__ C)
{
    __shared__ __align__(16) char smem[64 * 1024];
    int bid = blockIdx.x;
    int swz = (bid & 7) * 128 + (bid >> 3);          // bijective, nwg=1024
    int bcol = (swz & 3) * 128;
    int brow = (swz >> 2) * 128;
    int tid = threadIdx.x, lane = tid & 63, w = tid >> 6;
    int wr = (w >> 1) * 64, wc = (w & 1) * 64;
    int am = lane & 15, ah = lane >> 4;

    auto stage = [&](int buf, int k0) {   // 8 load instructions per wave
        char* As = smem + buf * 32768;
        char* Bs = As + 16384;
#pragma unroll
        for (int r = 0; r < 4; ++r) {
            int o = r * 4096 + tid * 16;
            int row = o >> 7;
            int cb = (o & 127) ^ ((row & 7) << 4);
            gload16(A + (size_t)(brow + row) * XD + k0 + (cb >> 1), As + o);
            gload16(Bt + (size_t)(bcol + row) * XD + k0 + (cb >> 1), Bs + o);
        }
    };

    f4 acc[4][4] = {};
    auto compute = [&](int buf) {
        char* As = smem + buf * 32768;
        char* Bs = As + 16384;
#pragma unroll
        for (int s = 0; s < 2; ++s) {
            int cb = s * 64 + ah * 16;
            bfrag8 a[4], b[4];
#pragma unroll
            for (int f = 0; f < 4; ++f) {
                int ra = wr + f * 16 + am;
                a[f] = *(const bfrag8*)(As + ra * 128 + (cb ^ ((ra & 7) << 4)));
                int rb = wc + f * 16 + am;
                b[f] = *(const bfrag8*)(Bs + rb * 128 + (cb ^ ((rb & 7) << 4)));
            }
#pragma unroll
            for (int i = 0; i < 4; ++i)
#pragma unroll
                for (int j = 0; j < 4; ++j)
                    acc[i][j] = __builtin_amdgcn_mfma_f32_16x16x32_bf16(a[i], b[j], acc[i][j], 0, 0, 0);
        }
    };

    stage(0, 0);
    stage(1, 64);
    for (int kt = 0; kt < 8; ++kt) {
        asm volatile("s_waitcnt vmcnt(8)" ::: "memory");
        __builtin_amdgcn_s_barrier();
        compute(kt & 1);
        __builtin_amdgcn_s_barrier();
        stage(kt & 1, (kt + 2) * 64);
    }
    asm volatile("s_waitcnt vmcnt(8)" ::: "memory");
    __builtin_amdgcn_s_barrier();
    compute(0);
    asm volatile("s_waitcnt vmcnt(0)" ::: "memory");
    __builtin_amdgcn_s_barrier();
    compute(1);

#pragma unroll
    for (int i = 0; i < 4; ++i)
#pragma unroll
        for (int j = 0; j < 4; ++j) {
            int col = bcol + wc + j * 16 + am;
            float bb = bias[col];
#pragma unroll
            for (int r = 0; r < 4; ++r) {
                int row = brow + wr + i * 16 + ah * 4 + r;
                float v = fmaxf(acc[i][j][r] + bb, 0.0f);
                C[(size_t)row * 512 + col] = __float2bfloat16(v);
            }
        }
}

// ---------------- out = sigmoid(hid2 . w_o2 + b_o2) ----------------
__global__ __launch_bounds__(256) void out_kernel(const bf16* __restrict__ h2,
                                                  const float* __restrict__ w2,
                                                  const float* __restrict__ b2,
                                                  float* __restrict__ out) {
    int lane = threadIdx.x & 63;
    int row = blockIdx.x * 4 + (threadIdx.x >> 6);
    bfu8 hv;
    hv.v = *(const bfrag8*)(h2 + (size_t)row * 512 + lane * 8);
    float s = 0.0f;
#pragma unroll
    for (int j = 0; j < 8; ++j)
        s += __bfloat162float(hv.h[j]) * w2[lane * 8 + j];
#pragma unroll
    for (int off = 32; off; off >>= 1) s += __shfl_down(s, off, 64);
    if (lane == 0) out[row] = fast_sigmoid(s + b2[0]);
}

// ---------------- host ----------------
extern "C" void kernel_launch(void* const* d_in, const int* in_sizes, int n_in,
                              void* d_out, int out_size, void* d_ws, size_t ws_size,
                              hipStream_t stream) {
    const int din[5]  = {32, 64, 256, 128, 16};
    const int kpad[5] = {64, 64, 256, 128, 64};

    const float* feats[5];
    const float *w1f[5], *b1f[5], *w2f[5], *b2f[5];
    for (int t = 0; t < 5; ++t) {
        feats[t] = (const float*)d_in[t];
        w1f[t] = (const float*)d_in[8 + 4 * t];
        b1f[t] = (const float*)d_in[9 + 4 * t];
        w2f[t] = (const float*)d_in[10 + 4 * t];
        b2f[t] = (const float*)d_in[11 + 4 * t];
    }
    const float* w_xou = (const float*)d_in[28];
    const float* b_xou = (const float*)d_in[29];
    const float* w_o1  = (const float*)d_in[30];
    const float* b_o1  = (const float*)d_in[31];
    const float* w_o2  = (const float*)d_in[32];
    const float* b_o2  = (const float*)d_in[33];

    float* outp = (float*)d_out;
    float* cc   = (float*)d_out + NN;

    char* ws = (char*)d_ws;
    size_t off = 0;
    auto take = [&](size_t bytes) -> char* {
        char* p = ws + off;
        off += (bytes + 255) & ~(size_t)255;
        return p;
    };
    bf16* w1t[5]; for (int t = 0; t < 5; ++t) w1t[t] = (bf16*)take((size_t)128 * kpad[t] * 2);
    bf16* w2t[5]; for (int t = 0; t < 5; ++t) w2t[t] = (bf16*)take((size_t)128 * 128 * 2);
    bf16* wxout = (bf16*)take((size_t)1920 * 640 * 2);
    bf16* wo1t  = (bf16*)take((size_t)512 * 640 * 2);
    bf16* hbf  = (bf16*)take((size_t)MP * XD * 2);
    bf16* xbf  = (bf16*)take((size_t)MP * XD * 2);   // x, later reused as hid2 [MP][512]
    float* ffb = (float*)take((size_t)MP * XD * 4);
    bf16* rrb  = (bf16*)take((size_t)MP * XD * 2);

    // 1) weight transpose-converts (one launch)
    WtArgs wa;
    int t0 = 0, si = 0;
    auto addseg = [&](const float* s, bf16* d, int K, int Nc, int kp) {
        wa.s[si++] = {s, d, K, Nc, kp, t0};
        t0 += (Nc / 64) * (kp / 64);
    };
    for (int t = 0; t < 5; ++t) addseg(w1f[t], w1t[t], din[t], 128, kpad[t]);
    for (int t = 0; t < 5; ++t) addseg(w2f[t], w2t[t], 128, 128, 128);
    addseg(w_xou, wxout, 640, 1920, 640);
    addseg(w_o1, wo1t, 640, 512, 640);
    wt_kernel<<<t0, 256, 0, stream>>>(wa);

    // 2) fused MLPs (f32 convert inline) -> x
    MlpArgs ma;
    for (int t = 0; t < 5; ++t) {
        ma.p[t] = {feats[t], w1t[t], b1f[t], w2t[t], b2f[t]};
        ma.din[t] = din[t]; ma.kpad[t] = kpad[t];
    }
    mlp_kernel<<<dim3(MP / 128, 5), 256, 0, stream>>>(ma, xbf);

    // 3) xou GEMM + fused gates (XCD-swizzled 1D grid)
    xou_kernel<<<2560, 256, 0, stream>>>(xbf, wxout, b_xou, ffb, rrb, cc);

    // 4) tree recursion (LDS) + h
    levels_h_kernel<<<dim3(NT, 20), 256, 0, stream>>>(cc, ffb, rrb, xbf, hbf);

    // 5) readout
    bf16* hid2 = xbf;
    gemm_db_kernel<<<1024, 256, 0, stream>>>(hbf, wo1t, b_o1, hid2);
    out_kernel<<<NN / 4, 256, 0, stream>>>(hid2, w_o2, b_o2, outp);
}

// Round 6
// 238.979 us; speedup vs baseline: 3.4729x; 1.0528x over previous
//
#include <hip/hip_runtime.h>
#include <hip/hip_bf16.h>

typedef __hip_bfloat16 bf16;
typedef __attribute__((ext_vector_type(8))) short bfrag8;  // 8 bf16 = 4 VGPRs
typedef __attribute__((ext_vector_type(4))) float f4;

#define NN 32704      // total nodes = 64 trees * 511
#define MP 32768      // M padded to 128-multiple
#define PT 511
#define NT 64
#define XD 640

union bfu8 { bfrag8 v; bf16 h[8]; };
union bfu4 { uint2 u; bf16 h[4]; };

__device__ __forceinline__ float fast_sigmoid(float x) {
    float e = exp2f(-1.44269504f * x);
    return __builtin_amdgcn_rcpf(1.0f + e);
}
__device__ __forceinline__ float fast_tanh(float x) {
    float e = exp2f(2.88539008f * x);
    return 1.0f - 2.0f * __builtin_amdgcn_rcpf(e + 1.0f);
}

// async global->LDS, 16B/lane. LDS dest linear; swizzle applied on GLOBAL source (m173).
__device__ __forceinline__ void gload16(const bf16* g, char* l) {
    __builtin_amdgcn_global_load_lds(
        (const __attribute__((address_space(1))) unsigned int*)(g),
        (__attribute__((address_space(3))) unsigned int*)(l), 16, 0, 0);
}

// ---------------- weight transpose-convert: all 12 weights, one launch ----------------
struct WtSeg { const float* src; bf16* dst; int K, Nc, kpad, tile0; };
struct WtArgs { WtSeg s[12]; };
__global__ __launch_bounds__(256) void wt_kernel(WtArgs a) {
    int bid = blockIdx.x;
    int si = 0;
#pragma unroll
    for (int i = 1; i < 12; ++i) if (bid >= a.s[i].tile0) si = i;
    WtSeg sg = a.s[si];
    int local = bid - sg.tile0;
    int kt = sg.kpad >> 6;
    int nb = local / kt, kb = local - nb * kt;
    int n0 = nb * 64, k0 = kb * 64;

    __shared__ float T[64][65];
    int tid = threadIdx.x;
    int kk = tid >> 2, nq = (tid & 3) * 16;
    bool kval = (k0 + kk) < sg.K;
    const float* srow = sg.src + (size_t)(k0 + kk) * sg.Nc + n0 + nq;
#pragma unroll
    for (int c = 0; c < 4; ++c) {
        float4 v = kval ? *(const float4*)(srow + c * 4) : float4{0, 0, 0, 0};
        T[kk][nq + c * 4 + 0] = v.x; T[kk][nq + c * 4 + 1] = v.y;
        T[kk][nq + c * 4 + 2] = v.z; T[kk][nq + c * 4 + 3] = v.w;
    }
    __syncthreads();
    int n = tid >> 2;
#pragma unroll
    for (int c = 0; c < 2; ++c) {
        int k8 = (tid & 3) * 2 + c;
        bfu8 u;
#pragma unroll
        for (int j = 0; j < 8; ++j) u.h[j] = __float2bfloat16(T[k8 * 8 + j][n]);
        *(bfrag8*)(sg.dst + (size_t)(n0 + n) * sg.kpad + k0 + k8 * 8) = u.v;
    }
}

// ---------------- fused MLP: f32-feat inline convert + 2 layers, hid1 in LDS ----------------
struct MlpP { const float* feat; const bf16* w1; const float* b1; const bf16* w2; const float* b2; };
struct MlpArgs { MlpP p[5]; int din[5]; int kpad[5]; };
__global__ __launch_bounds__(256) void mlp_kernel(MlpArgs args, bf16* __restrict__ out) {
    __shared__ __align__(16) char smem[64 * 1024];
    char* As = smem;            // [128][128B] feat k-tile (bf16, swizzled)
    char* Bs = smem + 16384;    // [128][128B] w1 k-tile
    char* Hs = smem + 32768;    // [128][256B] hid1 (bf16, swizzled)
    int t = blockIdx.y;
    int K = args.kpad[t], din = args.din[t];
    MlpP p = args.p[t];
    int tid = threadIdx.x, lane = tid & 63, w = tid >> 6;
    int brow = blockIdx.x * 128;
    int wr = (w >> 1) * 64, wc = (w & 1) * 64;
    int am = lane & 15, ah = lane >> 4;

    f4 acc[4][4] = {};
    for (int k0 = 0; k0 < K; k0 += 64) {
#pragma unroll
        for (int r = 0; r < 4; ++r) {
            int o = r * 4096 + tid * 16;
            int row = o >> 7;
            int cb = (o & 127) ^ ((row & 7) << 4);
            gload16(p.w1 + (size_t)row * K + k0 + (cb >> 1), Bs + o);
        }
        {
            int col0 = (tid & 7) * 8;
#pragma unroll
            for (int c = 0; c < 4; ++c) {
                int row = (tid >> 3) + c * 32;
                int grow = brow + row;
                bfu8 u; u.v = (bfrag8){0,0,0,0,0,0,0,0};
                int kc = k0 + col0;
                if (grow < NN && kc < din) {
                    const float* s = p.feat + (size_t)grow * din + kc;
                    float4 x = *(const float4*)s, y = *(const float4*)(s + 4);
                    u.h[0] = __float2bfloat16(x.x); u.h[1] = __float2bfloat16(x.y);
                    u.h[2] = __float2bfloat16(x.z); u.h[3] = __float2bfloat16(x.w);
                    u.h[4] = __float2bfloat16(y.x); u.h[5] = __float2bfloat16(y.y);
                    u.h[6] = __float2bfloat16(y.z); u.h[7] = __float2bfloat16(y.w);
                }
                *(bfrag8*)(As + row * 128 + ((col0 * 2) ^ ((row & 7) << 4))) = u.v;
            }
        }
        __syncthreads();
#pragma unroll
        for (int s = 0; s < 2; ++s) {
            int cb = s * 64 + ah * 16;
            bfrag8 a[4], b[4];
#pragma unroll
            for (int f = 0; f < 4; ++f) {
                int ra = wr + f * 16 + am;
                a[f] = *(const bfrag8*)(As + ra * 128 + (cb ^ ((ra & 7) << 4)));
                int rb = wc + f * 16 + am;
                b[f] = *(const bfrag8*)(Bs + rb * 128 + (cb ^ ((rb & 7) << 4)));
            }
#pragma unroll
            for (int i = 0; i < 4; ++i)
#pragma unroll
                for (int j = 0; j < 4; ++j)
                    acc[i][j] = __builtin_amdgcn_mfma_f32_16x16x32_bf16(a[i], b[j], acc[i][j], 0, 0, 0);
        }
        __syncthreads();
    }
#pragma unroll
    for (int i = 0; i < 4; ++i)
#pragma unroll
        for (int j = 0; j < 4; ++j) {
            int col = wc + j * 16 + am;
            float bb = p.b1[col];
#pragma unroll
            for (int r = 0; r < 4; ++r) {
                int row = wr + i * 16 + ah * 4 + r;
                float v = fmaxf(acc[i][j][r] + bb, 0.0f);
                *(bf16*)(Hs + row * 256 + ((col * 2) ^ ((row & 7) << 4))) = __float2bfloat16(v);
            }
        }
    __syncthreads();
    f4 acc2[4][4] = {};
#pragma unroll
    for (int ks = 0; ks < 4; ++ks) {
        bfrag8 a[4], b[4];
        int kb = ks * 64 + ah * 16;
#pragma unroll
        for (int f = 0; f < 4; ++f) {
            int ra = wr + f * 16 + am;
            a[f] = *(const bfrag8*)(Hs + ra * 256 + (kb ^ ((ra & 7) << 4)));
            int cbn = wc + f * 16 + am;
            b[f] = *(const bfrag8*)(p.w2 + (size_t)cbn * 128 + ks * 32 + ah * 8);
        }
#pragma unroll
        for (int i = 0; i < 4; ++i)
#pragma unroll
            for (int j = 0; j < 4; ++j)
                acc2[i][j] = __builtin_amdgcn_mfma_f32_16x16x32_bf16(a[i], b[j], acc2[i][j], 0, 0, 0);
    }
#pragma unroll
    for (int i = 0; i < 4; ++i)
#pragma unroll
        for (int j = 0; j < 4; ++j) {
            int col = wc + j * 16 + am;
            float bb = p.b2[col];
#pragma unroll
            for (int r = 0; r < 4; ++r) {
                int row = brow + wr + i * 16 + ah * 4 + r;
                float v = fmaxf(acc2[i][j][r] + bb, 0.0f);
                out[(size_t)row * XD + t * 128 + col] = __float2bfloat16(v);
            }
        }
}

// ---------------- xou GEMM: ring-of-4 half-tile pipeline (T3+T4+T5) ----------------
// BK=32 half-tiles, 4 LDS bufs (80 KB), 3 half-tiles in flight, stage overlaps MFMA.
// LDS rows are 64B; slot swizzle: phys_slot = k_frag ^ ((row>>1)&3) -> 8 banks x 2 lanes.
#define HBUF 20480   // 8192 A + 12288 B
__global__ __launch_bounds__(256) void xou_kernel(
    const bf16* __restrict__ X, const bf16* __restrict__ Wt,
    const float* __restrict__ bias,
    bf16* __restrict__ ffp, bf16* __restrict__ rrp, float* __restrict__ cc)
{
    __shared__ __align__(16) char smem[4 * HBUF];
    int bid = blockIdx.x;
    int swz = (bid & 7) * 320 + (bid >> 3);          // bijective XCD swizzle, nwg=2560
    int bcol = (swz % 10) * 64;
    int brow = (swz / 10) * 128;
    int tid = threadIdx.x, lane = tid & 63, w = tid >> 6;
    int wr = (w >> 1) * 64, wc = (w & 1) * 32;
    int am = lane & 15, ah = lane >> 4;

    auto stage = [&](int b, int ht) {   // 5 load instructions per thread-round set
        char* As = smem + b * HBUF;
        char* Bs = As + 8192;
        int k0 = ht * 32;
#pragma unroll
        for (int r = 0; r < 2; ++r) {
            int o = r * 4096 + tid * 16;
            int row = o >> 6;                       // 64B rows
            int ksl = ((o >> 4) & 3) ^ ((row >> 1) & 3);
            gload16(X + (size_t)(brow + row) * XD + k0 + ksl * 8, As + o);
        }
#pragma unroll
        for (int r = 0; r < 3; ++r) {
            int o = r * 4096 + tid * 16;
            int row = o >> 6;                       // 0..191 = q*64+rl
            int ksl = ((o >> 4) & 3) ^ ((row >> 1) & 3);
            int q = row >> 6, rl = row & 63;
            gload16(Wt + (size_t)(q * 640 + bcol + rl) * XD + k0 + ksl * 8, Bs + o);
        }
    };

    f4 acc[3][4][2] = {};
    stage(0, 0); stage(1, 1); stage(2, 2);
    for (int h = 0; h < 20; ++h) {
        if (h <= 17)      asm volatile("s_waitcnt vmcnt(10)" ::: "memory");
        else if (h == 18) asm volatile("s_waitcnt vmcnt(5)"  ::: "memory");
        else              asm volatile("s_waitcnt vmcnt(0)"  ::: "memory");
        __builtin_amdgcn_s_barrier();
        int b = h & 3;
        char* As = smem + b * HBUF;
        char* Bs = As + 8192;
        bfrag8 a[4], bb[3][2];
#pragma unroll
        for (int f = 0; f < 4; ++f) {
            int ra = wr + f * 16 + am;
            a[f] = *(const bfrag8*)(As + ra * 64 + ((ah ^ ((ra >> 1) & 3)) << 4));
        }
#pragma unroll
        for (int q = 0; q < 3; ++q)
#pragma unroll
            for (int f = 0; f < 2; ++f) {
                int rb = q * 64 + wc + f * 16 + am;
                bb[q][f] = *(const bfrag8*)(Bs + rb * 64 + ((ah ^ ((rb >> 1) & 3)) << 4));
            }
        if (h + 3 < 20) stage((h + 3) & 3, h + 3);   // overlaps MFMA below; buf free since h-1
        __builtin_amdgcn_s_setprio(1);
#pragma unroll
        for (int q = 0; q < 3; ++q)
#pragma unroll
            for (int i = 0; i < 4; ++i)
#pragma unroll
                for (int j = 0; j < 2; ++j)
                    acc[q][i][j] = __builtin_amdgcn_mfma_f32_16x16x32_bf16(a[i], bb[q][j], acc[q][i][j], 0, 0, 0);
        __builtin_amdgcn_s_setprio(0);
        __builtin_amdgcn_s_barrier();
    }

#pragma unroll
    for (int i = 0; i < 4; ++i)
#pragma unroll
        for (int j = 0; j < 2; ++j) {
            int col = bcol + wc + j * 16 + am;
            float bxx = bias[col], bff = bias[640 + col], brr = bias[1280 + col];
#pragma unroll
            for (int r = 0; r < 4; ++r) {
                int row = brow + wr + i * 16 + ah * 4 + r;
                size_t o = (size_t)row * XD + col;
                float xx = acc[0][i][j][r] + bxx;
                float fv = fast_sigmoid(acc[1][i][j][r] + bff);
                float rv = fast_sigmoid(acc[2][i][j][r] + brr);
                unsigned pl = (unsigned)row % 511u;
                if (pl < 255u) ffp[o] = __float2bfloat16(fv);  // ff read only for internal nodes
                rrp[o] = __float2bfloat16(rv);
                if (row < NN) cc[o] = (1.0f - fv) * xx;
            }
        }
}

// ---------------- tree recursion in LDS + h, one launch ----------------
__device__ __forceinline__ int clidx(int node, int e) {
    int g = e & ~3;
    return node * 32 + (g ^ ((node & 7) * 4)) + (e & 3);
}
__global__ __launch_bounds__(256) void levels_h_kernel(
    float* __restrict__ c, const bf16* __restrict__ ff,
    const bf16* __restrict__ rr, const bf16* __restrict__ x, bf16* __restrict__ h) {
    __shared__ __align__(16) float cl[511 * 32];   // 65,408 B
    int t = blockIdx.x, d0 = blockIdx.y * 32;
    size_t tb = (size_t)t * PT;
    int tid = threadIdx.x;

    for (int it = tid; it < 511 * 8; it += 256) {
        int node = it >> 3, q = (it & 7) * 4;
        *(float4*)&cl[clidx(node, q)] = *(const float4*)(c + (tb + node) * XD + d0 + q);
    }
    __syncthreads();

    for (int n = 1; n <= 8; ++n) {
        int cnt = 1 << (8 - n);
        for (int it = tid; it < cnt * 8; it += 256) {
            int pl = (cnt - 1) + (it >> 3), q = (it & 7) * 4;
            bfu4 fu; fu.u = *(const uint2*)(ff + (tb + pl) * XD + d0 + q);
            float4 l  = *(const float4*)&cl[clidx(2 * pl + 1, q)];
            float4 rg = *(const float4*)&cl[clidx(2 * pl + 2, q)];
            float4 cv = *(const float4*)&cl[clidx(pl, q)];
            cv.x += __bfloat162float(fu.h[0]) * (l.x + rg.x);
            cv.y += __bfloat162float(fu.h[1]) * (l.y + rg.y);
            cv.z += __bfloat162float(fu.h[2]) * (l.z + rg.z);
            cv.w += __bfloat162float(fu.h[3]) * (l.w + rg.w);
            *(float4*)&cl[clidx(pl, q)] = cv;
        }
        __syncthreads();
    }

    for (int it = tid; it < 255 * 8; it += 256) {
        int pl = it >> 3, q = (it & 7) * 4;
        *(float4*)(c + (tb + pl) * XD + d0 + q) = *(const float4*)&cl[clidx(pl, q)];
    }
    for (int it = tid; it < 511 * 4; it += 256) {
        int node = it >> 2, q = (it & 3) * 8;
        size_t o = (tb + node) * XD + d0 + q;
        bfu8 rv, xv, ov;
        rv.v = *(const bfrag8*)(rr + o);
        xv.v = *(const bfrag8*)(x + o);
        float4 c0 = *(const float4*)&cl[clidx(node, q)];
        float4 c1 = *(const float4*)&cl[clidx(node, q + 4)];
        float cv[8] = {c0.x, c0.y, c0.z, c0.w, c1.x, c1.y, c1.z, c1.w};
#pragma unroll
        for (int j = 0; j < 8; ++j) {
            float r = __bfloat162float(rv.h[j]);
            float xb = __bfloat162float(xv.h[j]);
            ov.h[j] = __float2bfloat16(r * fast_tanh(cv[j]) + (1.0f - r) * xb);
        }
        *(bfrag8*)(h + o) = ov.v;
    }
}

// ---------------- o1 GEMM fused with w_o2 dot: atomicAdd partial row sums ----------------
__global__ __launch_bounds__(256) void gemm_db_kernel(
    const bf16* __restrict__ A, const bf16* __restrict__ Bt,
    const float* __restrict__ bias, const float* __restrict__ w2,
    float* __restrict__ outacc)
{
    __shared__ __align__(16) char smem[64 * 1024];
    int bid = blockIdx.x;
    int swz = (bid & 7) * 128 + (bid >> 3);          // bijective, nwg=1024
    int bcol = (swz & 3) * 128;
    int brow = (swz >> 2) * 128;
    int tid = threadIdx.x, lane = tid & 63, w = tid >> 6;
    int wr = (w >> 1) * 64, wc = (w & 1) * 64;
    int am = lane & 15, ah = lane >> 4;

    auto stage = [&](int buf, int k0) {
        char* As = smem + buf * 32768;
        char* Bs = As + 16384;
#pragma unroll
        for (int r = 0; r < 4; ++r) {
            int o = r * 4096 + tid * 16;
            int row = o >> 7;
            int cb = (o & 127) ^ ((row & 7) << 4);
            gload16(A + (size_t)(brow + row) * XD + k0 + (cb >> 1), As + o);
            gload16(Bt + (size_t)(bcol + row) * XD + k0 + (cb >> 1), Bs + o);
        }
    };

    f4 acc[4][4] = {};
    auto compute = [&](int buf) {
        char* As = smem + buf * 32768;
        char* Bs = As + 16384;
#pragma unroll
        for (int s = 0; s < 2; ++s) {
            int cb = s * 64 + ah * 16;
            bfrag8 a[4], b[4];
#pragma unroll
            for (int f = 0; f < 4; ++f) {
                int ra = wr + f * 16 + am;
                a[f] = *(const bfrag8*)(As + ra * 128 + (cb ^ ((ra & 7) << 4)));
                int rb = wc + f * 16 + am;
                b[f] = *(const bfrag8*)(Bs + rb * 128 + (cb ^ ((rb & 7) << 4)));
            }
#pragma unroll
            for (int i = 0; i < 4; ++i)
#pragma unroll
                for (int j = 0; j < 4; ++j)
                    acc[i][j] = __builtin_amdgcn_mfma_f32_16x16x32_bf16(a[i], b[j], acc[i][j], 0, 0, 0);
        }
    };

    stage(0, 0);
    stage(1, 64);
    for (int kt = 0; kt < 8; ++kt) {
        asm volatile("s_waitcnt vmcnt(8)" ::: "memory");
        __builtin_amdgcn_s_barrier();
        compute(kt & 1);
        __builtin_amdgcn_s_barrier();
        stage(kt & 1, (kt + 2) * 64);
    }
    asm volatile("s_waitcnt vmcnt(8)" ::: "memory");
    __builtin_amdgcn_s_barrier();
    compute(0);
    asm volatile("s_waitcnt vmcnt(0)" ::: "memory");
    __builtin_amdgcn_s_barrier();
    compute(1);

    // epilogue: hid2 = relu(acc+bias); partial dot with w_o2 cols; reduce over 16 lanes; atomic
    float w2v[4];
#pragma unroll
    for (int j = 0; j < 4; ++j) w2v[j] = w2[bcol + wc + j * 16 + am];
#pragma unroll
    for (int i = 0; i < 4; ++i) {
        float ps[4] = {0.0f, 0.0f, 0.0f, 0.0f};
#pragma unroll
        for (int j = 0; j < 4; ++j) {
            float bb = bias[bcol + wc + j * 16 + am];
#pragma unroll
            for (int r = 0; r < 4; ++r)
                ps[r] += fmaxf(acc[i][j][r] + bb, 0.0f) * w2v[j];
        }
#pragma unroll
        for (int r = 0; r < 4; ++r) {
            float s = ps[r];
            s += __shfl_xor(s, 1, 64);
            s += __shfl_xor(s, 2, 64);
            s += __shfl_xor(s, 4, 64);
            s += __shfl_xor(s, 8, 64);
            if (am == 0) {
                int row = brow + wr + i * 16 + ah * 4 + r;
                if (row < NN) atomicAdd(outacc + row, s);
            }
        }
    }
}

// ---------------- out = sigmoid(acc + b_o2) ----------------
__global__ void sig_kernel(const float* __restrict__ acc, const float* __restrict__ b2,
                           float* __restrict__ out) {
    int i = blockIdx.x * 256 + threadIdx.x;
    if (i < NN) out[i] = fast_sigmoid(acc[i] + b2[0]);
}

// ---------------- host ----------------
extern "C" void kernel_launch(void* const* d_in, const int* in_sizes, int n_in,
                              void* d_out, int out_size, void* d_ws, size_t ws_size,
                              hipStream_t stream) {
    const int din[5]  = {32, 64, 256, 128, 16};
    const int kpad[5] = {64, 64, 256, 128, 64};

    const float* feats[5];
    const float *w1f[5], *b1f[5], *w2f[5], *b2f[5];
    for (int t = 0; t < 5; ++t) {
        feats[t] = (const float*)d_in[t];
        w1f[t] = (const float*)d_in[8 + 4 * t];
        b1f[t] = (const float*)d_in[9 + 4 * t];
        w2f[t] = (const float*)d_in[10 + 4 * t];
        b2f[t] = (const float*)d_in[11 + 4 * t];
    }
    const float* w_xou = (const float*)d_in[28];
    const float* b_xou = (const float*)d_in[29];
    const float* w_o1  = (const float*)d_in[30];
    const float* b_o1  = (const float*)d_in[31];
    const float* w_o2  = (const float*)d_in[32];
    const float* b_o2  = (const float*)d_in[33];

    float* outp = (float*)d_out;
    float* cc   = (float*)d_out + NN;

    char* ws = (char*)d_ws;
    size_t off = 0;
    auto take = [&](size_t bytes) -> char* {
        char* p = ws + off;
        off += (bytes + 255) & ~(size_t)255;
        return p;
    };
    bf16* w1t[5]; for (int t = 0; t < 5; ++t) w1t[t] = (bf16*)take((size_t)128 * kpad[t] * 2);
    bf16* w2t[5]; for (int t = 0; t < 5; ++t) w2t[t] = (bf16*)take((size_t)128 * 128 * 2);
    bf16* wxout = (bf16*)take((size_t)1920 * 640 * 2);
    bf16* wo1t  = (bf16*)take((size_t)512 * 640 * 2);
    bf16* hbf   = (bf16*)take((size_t)MP * XD * 2);
    bf16* xbf   = (bf16*)take((size_t)MP * XD * 2);
    bf16* ffb   = (bf16*)take((size_t)MP * XD * 2);
    bf16* rrb   = (bf16*)take((size_t)MP * XD * 2);
    float* outacc = (float*)take((size_t)MP * 4);

    // 1) weight transpose-converts (one launch)
    WtArgs wa;
    int t0 = 0, si = 0;
    auto addseg = [&](const float* s, bf16* d, int K, int Nc, int kp) {
        wa.s[si++] = {s, d, K, Nc, kp, t0};
        t0 += (Nc / 64) * (kp / 64);
    };
    for (int t = 0; t < 5; ++t) addseg(w1f[t], w1t[t], din[t], 128, kpad[t]);
    for (int t = 0; t < 5; ++t) addseg(w2f[t], w2t[t], 128, 128, 128);
    addseg(w_xou, wxout, 640, 1920, 640);
    addseg(w_o1, wo1t, 640, 512, 640);
    wt_kernel<<<t0, 256, 0, stream>>>(wa);

    // 2) fused MLPs (f32 convert inline) -> x
    MlpArgs ma;
    for (int t = 0; t < 5; ++t) {
        ma.p[t] = {feats[t], w1t[t], b1f[t], w2t[t], b2f[t]};
        ma.din[t] = din[t]; ma.kpad[t] = kpad[t];
    }
    mlp_kernel<<<dim3(MP / 128, 5), 256, 0, stream>>>(ma, xbf);

    // 3) xou GEMM + fused gates (ring-4 pipeline, XCD-swizzled)
    xou_kernel<<<2560, 256, 0, stream>>>(xbf, wxout, b_xou, ffb, rrb, cc);

    // 4) tree recursion (LDS) + h
    levels_h_kernel<<<dim3(NT, 20), 256, 0, stream>>>(cc, ffb, rrb, xbf, hbf);

    // 5) readout: o1 GEMM fused with w_o2 dot -> outacc, then sigmoid
    hipMemsetAsync(outacc, 0, (size_t)MP * 4, stream);
    gemm_db_kernel<<<1024, 256, 0, stream>>>(hbf, wo1t, b_o1, w_o2, outacc);
    sig_kernel<<<(NN + 255) / 256, 256, 0, stream>>>(outacc, b_o2, outp);
}

// Round 7
// 229.364 us; speedup vs baseline: 3.6185x; 1.0419x over previous
//
#include <hip/hip_runtime.h>
#include <hip/hip_bf16.h>

typedef __hip_bfloat16 bf16;
typedef __attribute__((ext_vector_type(8))) short bfrag8;  // 8 bf16 = 4 VGPRs
typedef __attribute__((ext_vector_type(4))) float f4;

#define NN 32704      // total nodes = 64 trees * 511
#define MP 32768      // M padded to 128-multiple
#define PT 511
#define NT 64
#define XD 640

union bfu8 { bfrag8 v; bf16 h[8]; };
union bfu4 { uint2 u; bf16 h[4]; };

__device__ __forceinline__ float fast_sigmoid(float x) {
    float e = exp2f(-1.44269504f * x);
    return __builtin_amdgcn_rcpf(1.0f + e);
}
__device__ __forceinline__ float fast_tanh(float x) {
    float e = exp2f(2.88539008f * x);
    return 1.0f - 2.0f * __builtin_amdgcn_rcpf(e + 1.0f);
}

// async global->LDS, 16B/lane. LDS dest linear; swizzle applied on GLOBAL source (m173).
__device__ __forceinline__ void gload16(const bf16* g, char* l) {
    __builtin_amdgcn_global_load_lds(
        (const __attribute__((address_space(1))) unsigned int*)(g),
        (__attribute__((address_space(3))) unsigned int*)(l), 16, 0, 0);
}

// ---------------- weight transpose-convert: all 12 weights, one launch ----------------
struct WtSeg { const float* src; bf16* dst; int K, Nc, kpad, tile0; };
struct WtArgs { WtSeg s[12]; };
__global__ __launch_bounds__(256) void wt_kernel(WtArgs a) {
    int bid = blockIdx.x;
    int si = 0;
#pragma unroll
    for (int i = 1; i < 12; ++i) if (bid >= a.s[i].tile0) si = i;
    WtSeg sg = a.s[si];
    int local = bid - sg.tile0;
    int kt = sg.kpad >> 6;
    int nb = local / kt, kb = local - nb * kt;
    int n0 = nb * 64, k0 = kb * 64;

    __shared__ float T[64][65];
    int tid = threadIdx.x;
    int kk = tid >> 2, nq = (tid & 3) * 16;
    bool kval = (k0 + kk) < sg.K;
    const float* srow = sg.src + (size_t)(k0 + kk) * sg.Nc + n0 + nq;
#pragma unroll
    for (int c = 0; c < 4; ++c) {
        float4 v = kval ? *(const float4*)(srow + c * 4) : float4{0, 0, 0, 0};
        T[kk][nq + c * 4 + 0] = v.x; T[kk][nq + c * 4 + 1] = v.y;
        T[kk][nq + c * 4 + 2] = v.z; T[kk][nq + c * 4 + 3] = v.w;
    }
    __syncthreads();
    int n = tid >> 2;
#pragma unroll
    for (int c = 0; c < 2; ++c) {
        int k8 = (tid & 3) * 2 + c;
        bfu8 u;
#pragma unroll
        for (int j = 0; j < 8; ++j) u.h[j] = __float2bfloat16(T[k8 * 8 + j][n]);
        *(bfrag8*)(sg.dst + (size_t)(n0 + n) * sg.kpad + k0 + k8 * 8) = u.v;
    }
}

// ---------------- fused MLP: f32-feat inline convert + 2 layers, hid1 in LDS ----------------
struct MlpP { const float* feat; const bf16* w1; const float* b1; const bf16* w2; const float* b2; };
struct MlpArgs { MlpP p[5]; int din[5]; int kpad[5]; };
__global__ __launch_bounds__(256) void mlp_kernel(MlpArgs args, bf16* __restrict__ out) {
    __shared__ __align__(16) char smem[64 * 1024];
    char* As = smem;            // [128][128B] feat k-tile (bf16, swizzled)
    char* Bs = smem + 16384;    // [128][128B] w1 k-tile
    char* Hs = smem + 32768;    // [128][256B] hid1 (bf16, swizzled)
    int t = blockIdx.y;
    int K = args.kpad[t], din = args.din[t];
    MlpP p = args.p[t];
    int tid = threadIdx.x, lane = tid & 63, w = tid >> 6;
    int brow = blockIdx.x * 128;
    int wr = (w >> 1) * 64, wc = (w & 1) * 64;
    int am = lane & 15, ah = lane >> 4;

    f4 acc[4][4] = {};
    for (int k0 = 0; k0 < K; k0 += 64) {
#pragma unroll
        for (int r = 0; r < 4; ++r) {
            int o = r * 4096 + tid * 16;
            int row = o >> 7;
            int cb = (o & 127) ^ ((row & 7) << 4);
            gload16(p.w1 + (size_t)row * K + k0 + (cb >> 1), Bs + o);
        }
        {
            int col0 = (tid & 7) * 8;
#pragma unroll
            for (int c = 0; c < 4; ++c) {
                int row = (tid >> 3) + c * 32;
                int grow = brow + row;
                bfu8 u; u.v = (bfrag8){0,0,0,0,0,0,0,0};
                int kc = k0 + col0;
                if (grow < NN && kc < din) {
                    const float* s = p.feat + (size_t)grow * din + kc;
                    float4 x = *(const float4*)s, y = *(const float4*)(s + 4);
                    u.h[0] = __float2bfloat16(x.x); u.h[1] = __float2bfloat16(x.y);
                    u.h[2] = __float2bfloat16(x.z); u.h[3] = __float2bfloat16(x.w);
                    u.h[4] = __float2bfloat16(y.x); u.h[5] = __float2bfloat16(y.y);
                    u.h[6] = __float2bfloat16(y.z); u.h[7] = __float2bfloat16(y.w);
                }
                *(bfrag8*)(As + row * 128 + ((col0 * 2) ^ ((row & 7) << 4))) = u.v;
            }
        }
        __syncthreads();
#pragma unroll
        for (int s = 0; s < 2; ++s) {
            int cb = s * 64 + ah * 16;
            bfrag8 a[4], b[4];
#pragma unroll
            for (int f = 0; f < 4; ++f) {
                int ra = wr + f * 16 + am;
                a[f] = *(const bfrag8*)(As + ra * 128 + (cb ^ ((ra & 7) << 4)));
                int rb = wc + f * 16 + am;
                b[f] = *(const bfrag8*)(Bs + rb * 128 + (cb ^ ((rb & 7) << 4)));
            }
#pragma unroll
            for (int i = 0; i < 4; ++i)
#pragma unroll
                for (int j = 0; j < 4; ++j)
                    acc[i][j] = __builtin_amdgcn_mfma_f32_16x16x32_bf16(a[i], b[j], acc[i][j], 0, 0, 0);
        }
        __syncthreads();
    }
#pragma unroll
    for (int i = 0; i < 4; ++i)
#pragma unroll
        for (int j = 0; j < 4; ++j) {
            int col = wc + j * 16 + am;
            float bb = p.b1[col];
#pragma unroll
            for (int r = 0; r < 4; ++r) {
                int row = wr + i * 16 + ah * 4 + r;
                float v = fmaxf(acc[i][j][r] + bb, 0.0f);
                *(bf16*)(Hs + row * 256 + ((col * 2) ^ ((row & 7) << 4))) = __float2bfloat16(v);
            }
        }
    __syncthreads();
    f4 acc2[4][4] = {};
#pragma unroll
    for (int ks = 0; ks < 4; ++ks) {
        bfrag8 a[4], b[4];
        int kb = ks * 64 + ah * 16;
#pragma unroll
        for (int f = 0; f < 4; ++f) {
            int ra = wr + f * 16 + am;
            a[f] = *(const bfrag8*)(Hs + ra * 256 + (kb ^ ((ra & 7) << 4)));
            int cbn = wc + f * 16 + am;
            b[f] = *(const bfrag8*)(p.w2 + (size_t)cbn * 128 + ks * 32 + ah * 8);
        }
#pragma unroll
        for (int i = 0; i < 4; ++i)
#pragma unroll
            for (int j = 0; j < 4; ++j)
                acc2[i][j] = __builtin_amdgcn_mfma_f32_16x16x32_bf16(a[i], b[j], acc2[i][j], 0, 0, 0);
    }
#pragma unroll
    for (int i = 0; i < 4; ++i)
#pragma unroll
        for (int j = 0; j < 4; ++j) {
            int col = wc + j * 16 + am;
            float bb = p.b2[col];
#pragma unroll
            for (int r = 0; r < 4; ++r) {
                int row = brow + wr + i * 16 + ah * 4 + r;
                float v = fmaxf(acc2[i][j][r] + bb, 0.0f);
                out[(size_t)row * XD + t * 128 + col] = __float2bfloat16(v);
            }
        }
}

// ---------------- xou GEMM: 2-buf BK=64 counted-vmcnt (r5 schedule) + T5 setprio ----------------
// 1D grid 2560, bijective XCD swizzle; bf16 ff epilogue.
__global__ __launch_bounds__(256) void xou_kernel(
    const bf16* __restrict__ X, const bf16* __restrict__ Wt,
    const float* __restrict__ bias,
    bf16* __restrict__ ffp, bf16* __restrict__ rrp, float* __restrict__ cc)
{
    __shared__ __align__(16) char smem[80 * 1024];   // 2 x (A 16K + B 24K)
    int bid = blockIdx.x;
    int swz = (bid & 7) * 320 + (bid >> 3);          // bijective XCD swizzle, nwg=2560
    int bcol = (swz % 10) * 64;
    int brow = (swz / 10) * 128;
    int tid = threadIdx.x, lane = tid & 63, w = tid >> 6;
    int wr = (w >> 1) * 64, wc = (w & 1) * 32;
    int am = lane & 15, ah = lane >> 4;

    auto stage = [&](int buf, int k0) {   // 10 load instructions per lane
        char* As = smem + buf * 40960;
        char* Bs = As + 16384;
#pragma unroll
        for (int r = 0; r < 4; ++r) {
            int o = r * 4096 + tid * 16;
            int row = o >> 7;
            int cb = (o & 127) ^ ((row & 7) << 4);
            gload16(X + (size_t)(brow + row) * XD + k0 + (cb >> 1), As + o);
        }
#pragma unroll
        for (int r = 0; r < 6; ++r) {
            int o = r * 4096 + tid * 16;
            int row = o >> 7;
            int q = row >> 6, rl = row & 63;
            int cb = (o & 127) ^ ((row & 7) << 4);
            gload16(Wt + (size_t)(q * 640 + bcol + rl) * XD + k0 + (cb >> 1), Bs + o);
        }
    };

    f4 acc[3][4][2] = {};
    auto compute = [&](int buf) {
        char* As = smem + buf * 40960;
        char* Bs = As + 16384;
#pragma unroll
        for (int s = 0; s < 2; ++s) {
            int cb = s * 64 + ah * 16;
            bfrag8 a[4], b[3][2];
#pragma unroll
            for (int f = 0; f < 4; ++f) {
                int ra = wr + f * 16 + am;
                a[f] = *(const bfrag8*)(As + ra * 128 + (cb ^ ((ra & 7) << 4)));
            }
#pragma unroll
            for (int q = 0; q < 3; ++q)
#pragma unroll
                for (int f = 0; f < 2; ++f) {
                    int rb = wc + f * 16 + am;
                    b[q][f] = *(const bfrag8*)(Bs + q * 8192 + rb * 128 + (cb ^ ((rb & 7) << 4)));
                }
            __builtin_amdgcn_s_setprio(1);
#pragma unroll
            for (int q = 0; q < 3; ++q)
#pragma unroll
                for (int i = 0; i < 4; ++i)
#pragma unroll
                    for (int j = 0; j < 2; ++j)
                        acc[q][i][j] = __builtin_amdgcn_mfma_f32_16x16x32_bf16(a[i], b[q][j], acc[q][i][j], 0, 0, 0);
            __builtin_amdgcn_s_setprio(0);
        }
    };

    stage(0, 0);
    stage(1, 64);
    for (int kt = 0; kt < 8; ++kt) {
        asm volatile("s_waitcnt vmcnt(10)" ::: "memory");  // tile kt landed; kt+1 in flight
        __builtin_amdgcn_s_barrier();
        compute(kt & 1);
        __builtin_amdgcn_s_barrier();                      // all waves done reading before overwrite
        stage(kt & 1, (kt + 2) * 64);
    }
    asm volatile("s_waitcnt vmcnt(10)" ::: "memory");
    __builtin_amdgcn_s_barrier();
    compute(0);
    asm volatile("s_waitcnt vmcnt(0)" ::: "memory");
    __builtin_amdgcn_s_barrier();
    compute(1);

#pragma unroll
    for (int i = 0; i < 4; ++i)
#pragma unroll
        for (int j = 0; j < 2; ++j) {
            int col = bcol + wc + j * 16 + am;
            float bxx = bias[col], bff = bias[640 + col], brr = bias[1280 + col];
#pragma unroll
            for (int r = 0; r < 4; ++r) {
                int row = brow + wr + i * 16 + ah * 4 + r;
                size_t o = (size_t)row * XD + col;
                float xx = acc[0][i][j][r] + bxx;
                float fv = fast_sigmoid(acc[1][i][j][r] + bff);
                float rv = fast_sigmoid(acc[2][i][j][r] + brr);
                unsigned pl = (unsigned)row % 511u;
                if (pl < 255u) ffp[o] = __float2bfloat16(fv);  // ff read only for internal nodes
                rrp[o] = __float2bfloat16(rv);
                if (row < NN) cc[o] = (1.0f - fv) * xx;
            }
        }
}

// ---------------- tree recursion in LDS + h, one launch ----------------
__device__ __forceinline__ int clidx(int node, int e) {
    int g = e & ~3;
    return node * 32 + (g ^ ((node & 7) * 4)) + (e & 3);
}
__global__ __launch_bounds__(256) void levels_h_kernel(
    float* __restrict__ c, const bf16* __restrict__ ff,
    const bf16* __restrict__ rr, const bf16* __restrict__ x, bf16* __restrict__ h) {
    __shared__ __align__(16) float cl[511 * 32];   // 65,408 B
    int t = blockIdx.x, d0 = blockIdx.y * 32;
    size_t tb = (size_t)t * PT;
    int tid = threadIdx.x;

    for (int it = tid; it < 511 * 8; it += 256) {
        int node = it >> 3, q = (it & 7) * 4;
        *(float4*)&cl[clidx(node, q)] = *(const float4*)(c + (tb + node) * XD + d0 + q);
    }
    __syncthreads();

    for (int n = 1; n <= 8; ++n) {
        int cnt = 1 << (8 - n);
        for (int it = tid; it < cnt * 8; it += 256) {
            int pl = (cnt - 1) + (it >> 3), q = (it & 7) * 4;
            bfu4 fu; fu.u = *(const uint2*)(ff + (tb + pl) * XD + d0 + q);
            float4 l  = *(const float4*)&cl[clidx(2 * pl + 1, q)];
            float4 rg = *(const float4*)&cl[clidx(2 * pl + 2, q)];
            float4 cv = *(const float4*)&cl[clidx(pl, q)];
            cv.x += __bfloat162float(fu.h[0]) * (l.x + rg.x);
            cv.y += __bfloat162float(fu.h[1]) * (l.y + rg.y);
            cv.z += __bfloat162float(fu.h[2]) * (l.z + rg.z);
            cv.w += __bfloat162float(fu.h[3]) * (l.w + rg.w);
            *(float4*)&cl[clidx(pl, q)] = cv;
        }
        __syncthreads();
    }

    for (int it = tid; it < 255 * 8; it += 256) {
        int pl = it >> 3, q = (it & 7) * 4;
        *(float4*)(c + (tb + pl) * XD + d0 + q) = *(const float4*)&cl[clidx(pl, q)];
    }
    for (int it = tid; it < 511 * 4; it += 256) {
        int node = it >> 2, q = (it & 3) * 8;
        size_t o = (tb + node) * XD + d0 + q;
        bfu8 rv, xv, ov;
        rv.v = *(const bfrag8*)(rr + o);
        xv.v = *(const bfrag8*)(x + o);
        float4 c0 = *(const float4*)&cl[clidx(node, q)];
        float4 c1 = *(const float4*)&cl[clidx(node, q + 4)];
        float cv[8] = {c0.x, c0.y, c0.z, c0.w, c1.x, c1.y, c1.z, c1.w};
#pragma unroll
        for (int j = 0; j < 8; ++j) {
            float r = __bfloat162float(rv.h[j]);
            float xb = __bfloat162float(xv.h[j]);
            ov.h[j] = __float2bfloat16(r * fast_tanh(cv[j]) + (1.0f - r) * xb);
        }
        *(bfrag8*)(h + o) = ov.v;
    }
}

// ---------------- o1 GEMM fused with w_o2 dot: atomicAdd partial row sums ----------------
__global__ __launch_bounds__(256) void gemm_db_kernel(
    const bf16* __restrict__ A, const bf16* __restrict__ Bt,
    const float* __restrict__ bias, const float* __restrict__ w2,
    float* __restrict__ outacc)
{
    __shared__ __align__(16) char smem[64 * 1024];
    int bid = blockIdx.x;
    int swz = (bid & 7) * 128 + (bid >> 3);          // bijective, nwg=1024
    int bcol = (swz & 3) * 128;
    int brow = (swz >> 2) * 128;
    int tid = threadIdx.x, lane = tid & 63, w = tid >> 6;
    int wr = (w >> 1) * 64, wc = (w & 1) * 64;
    int am = lane & 15, ah = lane >> 4;

    auto stage = [&](int buf, int k0) {
        char* As = smem + buf * 32768;
        char* Bs = As + 16384;
#pragma unroll
        for (int r = 0; r < 4; ++r) {
            int o = r * 4096 + tid * 16;
            int row = o >> 7;
            int cb = (o & 127) ^ ((row & 7) << 4);
            gload16(A + (size_t)(brow + row) * XD + k0 + (cb >> 1), As + o);
            gload16(Bt + (size_t)(bcol + row) * XD + k0 + (cb >> 1), Bs + o);
        }
    };

    f4 acc[4][4] = {};
    auto compute = [&](int buf) {
        char* As = smem + buf * 32768;
        char* Bs = As + 16384;
#pragma unroll
        for (int s = 0; s < 2; ++s) {
            int cb = s * 64 + ah * 16;
            bfrag8 a[4], b[4];
#pragma unroll
            for (int f = 0; f < 4; ++f) {
                int ra = wr + f * 16 + am;
                a[f] = *(const bfrag8*)(As + ra * 128 + (cb ^ ((ra & 7) << 4)));
                int rb = wc + f * 16 + am;
                b[f] = *(const bfrag8*)(Bs + rb * 128 + (cb ^ ((rb & 7) << 4)));
            }
            __builtin_amdgcn_s_setprio(1);
#pragma unroll
            for (int i = 0; i < 4; ++i)
#pragma unroll
                for (int j = 0; j < 4; ++j)
                    acc[i][j] = __builtin_amdgcn_mfma_f32_16x16x32_bf16(a[i], b[j], acc[i][j], 0, 0, 0);
            __builtin_amdgcn_s_setprio(0);
        }
    };

    stage(0, 0);
    stage(1, 64);
    for (int kt = 0; kt < 8; ++kt) {
        asm volatile("s_waitcnt vmcnt(8)" ::: "memory");
        __builtin_amdgcn_s_barrier();
        compute(kt & 1);
        __builtin_amdgcn_s_barrier();
        stage(kt & 1, (kt + 2) * 64);
    }
    asm volatile("s_waitcnt vmcnt(8)" ::: "memory");
    __builtin_amdgcn_s_barrier();
    compute(0);
    asm volatile("s_waitcnt vmcnt(0)" ::: "memory");
    __builtin_amdgcn_s_barrier();
    compute(1);

    // epilogue: hid2 = relu(acc+bias); partial dot with w_o2 cols; reduce over 16 lanes; atomic
    float w2v[4];
#pragma unroll
    for (int j = 0; j < 4; ++j) w2v[j] = w2[bcol + wc + j * 16 + am];
#pragma unroll
    for (int i = 0; i < 4; ++i) {
        float ps[4] = {0.0f, 0.0f, 0.0f, 0.0f};
#pragma unroll
        for (int j = 0; j < 4; ++j) {
            float bb = bias[bcol + wc + j * 16 + am];
#pragma unroll
            for (int r = 0; r < 4; ++r)
                ps[r] += fmaxf(acc[i][j][r] + bb, 0.0f) * w2v[j];
        }
#pragma unroll
        for (int r = 0; r < 4; ++r) {
            float s = ps[r];
            s += __shfl_xor(s, 1, 64);
            s += __shfl_xor(s, 2, 64);
            s += __shfl_xor(s, 4, 64);
            s += __shfl_xor(s, 8, 64);
            if (am == 0) {
                int row = brow + wr + i * 16 + ah * 4 + r;
                if (row < NN) atomicAdd(outacc + row, s);
            }
        }
    }
}

// ---------------- out = sigmoid(acc + b_o2) ----------------
__global__ void sig_kernel(const float* __restrict__ acc, const float* __restrict__ b2,
                           float* __restrict__ out) {
    int i = blockIdx.x * 256 + threadIdx.x;
    if (i < NN) out[i] = fast_sigmoid(acc[i] + b2[0]);
}

// ---------------- host ----------------
extern "C" void kernel_launch(void* const* d_in, const int* in_sizes, int n_in,
                              void* d_out, int out_size, void* d_ws, size_t ws_size,
                              hipStream_t stream) {
    const int din[5]  = {32, 64, 256, 128, 16};
    const int kpad[5] = {64, 64, 256, 128, 64};

    const float* feats[5];
    const float *w1f[5], *b1f[5], *w2f[5], *b2f[5];
    for (int t = 0; t < 5; ++t) {
        feats[t] = (const float*)d_in[t];
        w1f[t] = (const float*)d_in[8 + 4 * t];
        b1f[t] = (const float*)d_in[9 + 4 * t];
        w2f[t] = (const float*)d_in[10 + 4 * t];
        b2f[t] = (const float*)d_in[11 + 4 * t];
    }
    const float* w_xou = (const float*)d_in[28];
    const float* b_xou = (const float*)d_in[29];
    const float* w_o1  = (const float*)d_in[30];
    const float* b_o1  = (const float*)d_in[31];
    const float* w_o2  = (const float*)d_in[32];
    const float* b_o2  = (const float*)d_in[33];

    float* outp = (float*)d_out;
    float* cc   = (float*)d_out + NN;

    char* ws = (char*)d_ws;
    size_t off = 0;
    auto take = [&](size_t bytes) -> char* {
        char* p = ws + off;
        off += (bytes + 255) & ~(size_t)255;
        return p;
    };
    bf16* w1t[5]; for (int t = 0; t < 5; ++t) w1t[t] = (bf16*)take((size_t)128 * kpad[t] * 2);
    bf16* w2t[5]; for (int t = 0; t < 5; ++t) w2t[t] = (bf16*)take((size_t)128 * 128 * 2);
    bf16* wxout = (bf16*)take((size_t)1920 * 640 * 2);
    bf16* wo1t  = (bf16*)take((size_t)512 * 640 * 2);
    bf16* hbf   = (bf16*)take((size_t)MP * XD * 2);
    bf16* xbf   = (bf16*)take((size_t)MP * XD * 2);
    bf16* ffb   = (bf16*)take((size_t)MP * XD * 2);
    bf16* rrb   = (bf16*)take((size_t)MP * XD * 2);
    float* outacc = (float*)take((size_t)MP * 4);

    // 1) weight transpose-converts (one launch)
    WtArgs wa;
    int t0 = 0, si = 0;
    auto addseg = [&](const float* s, bf16* d, int K, int Nc, int kp) {
        wa.s[si++] = {s, d, K, Nc, kp, t0};
        t0 += (Nc / 64) * (kp / 64);
    };
    for (int t = 0; t < 5; ++t) addseg(w1f[t], w1t[t], din[t], 128, kpad[t]);
    for (int t = 0; t < 5; ++t) addseg(w2f[t], w2t[t], 128, 128, 128);
    addseg(w_xou, wxout, 640, 1920, 640);
    addseg(w_o1, wo1t, 640, 512, 640);
    wt_kernel<<<t0, 256, 0, stream>>>(wa);

    // 2) fused MLPs (f32 convert inline) -> x
    MlpArgs ma;
    for (int t = 0; t < 5; ++t) {
        ma.p[t] = {feats[t], w1t[t], b1f[t], w2t[t], b2f[t]};
        ma.din[t] = din[t]; ma.kpad[t] = kpad[t];
    }
    mlp_kernel<<<dim3(MP / 128, 5), 256, 0, stream>>>(ma, xbf);

    // 3) xou GEMM + fused gates (2-buf BK=64 counted-vmcnt, XCD-swizzled)
    xou_kernel<<<2560, 256, 0, stream>>>(xbf, wxout, b_xou, ffb, rrb, cc);

    // 4) tree recursion (LDS) + h
    levels_h_kernel<<<dim3(NT, 20), 256, 0, stream>>>(cc, ffb, rrb, xbf, hbf);

    // 5) readout: o1 GEMM fused with w_o2 dot -> outacc, then sigmoid
    hipMemsetAsync(outacc, 0, (size_t)MP * 4, stream);
    gemm_db_kernel<<<1024, 256, 0, stream>>>(hbf, wo1t, b_o1, w_o2, outacc);
    sig_kernel<<<(NN + 255) / 256, 256, 0, stream>>>(outacc, b_o2, outp);
}